// Round 1
// 560.475 us; speedup vs baseline: 1.1313x; 1.1313x over previous
//
#include <hip/hip_runtime.h>
#include <hip/hip_bf16.h>

using bf16 = __hip_bfloat16;
typedef __attribute__((ext_vector_type(8))) short bf16x8;
typedef __attribute__((ext_vector_type(4))) float f32x4;

// Shapes fixed: B=2, S=2048, D=1024, H=16, hd=64, F=2048.
// Global I/O fp32. Batches sequential. ws = 16 MB = 4 bf16 regions r0..r3
// (2M elems each). d_out half (8 MB) doubles as scratch (obB as bf16).
//
// Per-batch lifetimes (stream-ordered, audited):
//  1  LN1(xb)            -> r3
//  2  WqT/WkT/WvT        -> obB[0:1M)/[1M:2M)/[2M:3M)
//  3  QKV mfma (z=0,1,2) -> r0,r1,r2   (A=r3, B=obB+z*1M, rope z<2)
//  4  vtrans: r2 (V)     -> obB[0:2M)  (V^T [16][64][2048]; WqT/WkT dead)
//  5  attn(r0,r1,Vt=obB) -> r2         (V natural dead)
//  6  WoT -> obB[2M:3M) (WvT dead); mode2: A=r2, B=WoT, res=xb -> x2=r3
//  7  LN2(r3)            -> r0 (h2; q dead)
//  8  W1T -> obB[0:2M) (Vt dead), W2T -> obB[2M:4M) (WoT dead)
//  9  mode0: A=r0, B=W1T -> u = r1 (spans r1..r2, [2048][2048])
// 10  mode3: A=r0, B=W2T, C=r1 in-place -> sb = silu(u)*g
// 11  W3T -> r0 (h2 dead)
// 12  mode4: A=r1, B=r0(W3T), res=r3(x2) -> ob fp32 (final)

__device__ inline float toF(float x) { return x; }
__device__ inline float toF(bf16 x) { return __bfloat162float(x); }
__device__ inline void  stV(float* p, float v) { *p = v; }
__device__ inline void  stV(bf16* p, float v) { *p = __float2bfloat16(v); }

__device__ __forceinline__ void unpack8(uint4 u, float* f) {
    f[0] = __uint_as_float(u.x << 16); f[1] = __uint_as_float(u.x & 0xffff0000u);
    f[2] = __uint_as_float(u.y << 16); f[3] = __uint_as_float(u.y & 0xffff0000u);
    f[4] = __uint_as_float(u.z << 16); f[5] = __uint_as_float(u.z & 0xffff0000u);
    f[6] = __uint_as_float(u.w << 16); f[7] = __uint_as_float(u.w & 0xffff0000u);
}

__device__ __forceinline__ uint4 packbf8(const float* f) {
    union { unsigned short u[8]; uint4 v; } r;
#pragma unroll
    for (int i = 0; i < 8; i++) {
        bf16 b = __float2bfloat16(f[i]);
        r.u[i] = *(unsigned short*)&b;
    }
    return r.v;
}

__device__ __forceinline__ unsigned pack2(float lo, float hi) {
    bf16 a = __float2bfloat16(lo), b = __float2bfloat16(hi);
    return ((unsigned)*(unsigned short*)&b << 16) | (unsigned)*(unsigned short*)&a;
}

__device__ __forceinline__ void gl_lds16(const void* g, void* l) {
    __builtin_amdgcn_global_load_lds(
        (__attribute__((address_space(1))) void*)g,
        (__attribute__((address_space(3))) void*)l, 16, 0, 0);
}

// ---------------------------------------------------------------------------
// LayerNorm: one block per row, D=1024, 256 threads.
// ---------------------------------------------------------------------------
template <typename Tx, typename To>
__global__ __launch_bounds__(256) void ln_kernel(
    const Tx* __restrict__ x, const float* __restrict__ g,
    const float* __restrict__ b, To* __restrict__ out)
{
    const int D = 1024;
    int row = blockIdx.x;
    int tid = threadIdx.x;
    const Tx* xr = x + (size_t)row * D;

    float vals[4];
    float sum = 0.f, sumsq = 0.f;
#pragma unroll
    for (int i = 0; i < 4; i++) {
        float v = toF(xr[tid + i * 256]);
        vals[i] = v; sum += v; sumsq += v * v;
    }
#pragma unroll
    for (int off = 32; off > 0; off >>= 1) {
        sum += __shfl_xor(sum, off);
        sumsq += __shfl_xor(sumsq, off);
    }
    __shared__ float s1[4], s2[4];
    int wave = tid >> 6, lane = tid & 63;
    if (lane == 0) { s1[wave] = sum; s2[wave] = sumsq; }
    __syncthreads();
    sum = s1[0] + s1[1] + s1[2] + s1[3];
    sumsq = s2[0] + s2[1] + s2[2] + s2[3];

    float mu = sum * (1.f / D);
    float var = sumsq * (1.f / D) - mu * mu;
    float rstd = rsqrtf(var + 1e-5f);

    To* orow = out + (size_t)row * D;
#pragma unroll
    for (int i = 0; i < 4; i++) {
        int c = tid + i * 256;
        stV(&orow[c], (vals[i] - mu) * rstd * g[c] + b[c]);
    }
}

// ---------------------------------------------------------------------------
// Transpose+convert: in fp32 [R][C] (per z-slice) -> out bf16 [C][R].
// ---------------------------------------------------------------------------
__global__ __launch_bounds__(256) void tconv_kernel(
    const float* __restrict__ in, bf16* __restrict__ out, int R, int C)
{
    __shared__ float t[32][33];
    int hh = blockIdx.z;
    const float* ip = in + (size_t)hh * R * C;
    bf16* op = out + (size_t)hh * R * C;
    int c0 = blockIdx.x * 32, r0 = blockIdx.y * 32;
    int tx = threadIdx.x & 31, ty = threadIdx.x >> 5;  // ty 0..7
#pragma unroll
    for (int i = 0; i < 4; i++)
        t[ty + 8 * i][tx] = ip[(size_t)(r0 + ty + 8 * i) * C + c0 + tx];
    __syncthreads();
#pragma unroll
    for (int i = 0; i < 4; i++)
        op[(size_t)(c0 + ty + 8 * i) * R + r0 + tx] = __float2bfloat16(t[tx][ty + 8 * i]);
}

// ---------------------------------------------------------------------------
// V transpose (bf16): v [16][2048][64] -> vt [16][64][2048]. 64x64 tiles.
// ---------------------------------------------------------------------------
__global__ __launch_bounds__(256) void vtrans_kernel(
    const bf16* __restrict__ v, bf16* __restrict__ vt)
{
    __shared__ unsigned short t[64][68];
    int hh = blockIdx.y;
    int s0 = blockIdx.x * 64;
    int tid = threadIdx.x;
    int r = tid >> 2, g = (tid & 3) * 16;

    const uint4* src = (const uint4*)(v + ((size_t)hh * 2048 + s0 + r) * 64 + g);
    *(uint4*)&t[r][g] = src[0];
    *(uint4*)&t[r][g + 8] = src[1];
    __syncthreads();

    union { unsigned short u[16]; uint4 v4[2]; } o;
#pragma unroll
    for (int i = 0; i < 16; i++) o.u[i] = t[g + i][r];
    uint4* dst = (uint4*)(vt + ((size_t)hh * 64 + r) * 2048 + s0 + g);
    dst[0] = o.v4[0];
    dst[1] = o.v4[1];
}

// ---------------------------------------------------------------------------
// MFMA GEMM: C[M,N] = A[M,K](bf16) @ B (BT[N,K] bf16), fp32 accum.
// 128x128 tile, BK=32, 4 waves (2x2), 4x4 16x16 MFMA subtiles per wave.
// MODE 0: C bf16 = acc
// MODE 1: QKV scatter [H][S][64] + RoPE (z selects B/C; rope for z<2)
// MODE 2: C bf16 = acc + resF32
// MODE 3: C bf16 = silu(C) * acc   (in-place, same idx)
// MODE 4: C f32  = acc + resBf16
// ---------------------------------------------------------------------------
template <int MODE>
__global__ __launch_bounds__(256) void mfma_gemm(
    const bf16* __restrict__ A, const bf16* __restrict__ BT0,
    void* __restrict__ Cv, const void* __restrict__ resv,
    int M, int N, int K)
{
    __shared__ bf16 As[128 * 32];
    __shared__ bf16 Bs[128 * 32];
    int tid = threadIdx.x, lane = tid & 63, w = tid >> 6;
    int wm = w >> 1, wn = w & 1;
    int m0 = blockIdx.y * 128, n0 = blockIdx.x * 128;

    const bf16* BT = BT0;
    bf16* Cq = nullptr; int rope = 0;
    if (MODE == 1) {
        int z = blockIdx.z;
        BT = BT0 + ((size_t)z << 20);
        Cq = (bf16*)Cv + ((size_t)z << 21);
        rope = (z < 2);
    }

    int srow = lane >> 2, scol = (lane & 3) * 8;
    const bf16* Ag = A + (size_t)(m0 + w * 32 + srow) * K + scol;
    const bf16* Bg = BT + (size_t)(n0 + w * 32 + srow) * K + scol;
    unsigned offAB = (unsigned)__builtin_amdgcn_readfirstlane(w * 2048);
    char* As_c = (char*)As;
    char* Bs_c = (char*)Bs;

    f32x4 acc[4][4];
#pragma unroll
    for (int i = 0; i < 4; i++)
#pragma unroll
        for (int j = 0; j < 4; j++) acc[i][j] = (f32x4){0.f, 0.f, 0.f, 0.f};

    for (int k0 = 0; k0 < K; k0 += 32) {
        gl_lds16(Ag + k0,                  As_c + offAB);
        gl_lds16(Ag + k0 + (size_t)16 * K, As_c + offAB + 1024);
        gl_lds16(Bg + k0,                  Bs_c + offAB);
        gl_lds16(Bg + k0 + (size_t)16 * K, Bs_c + offAB + 1024);
        __syncthreads();

        bf16x8 af[4], bfr[4];
#pragma unroll
        for (int i = 0; i < 4; i++)
            af[i] = *(const bf16x8*)&As[(wm * 64 + i * 16 + (lane & 15)) * 32 + (lane >> 4) * 8];
#pragma unroll
        for (int j = 0; j < 4; j++)
            bfr[j] = *(const bf16x8*)&Bs[(wn * 64 + j * 16 + (lane & 15)) * 32 + (lane >> 4) * 8];
#pragma unroll
        for (int i = 0; i < 4; i++)
#pragma unroll
            for (int j = 0; j < 4; j++)
                acc[i][j] = __builtin_amdgcn_mfma_f32_16x16x32_bf16(af[i], bfr[j], acc[i][j], 0, 0, 0);
        __syncthreads();
    }

    int rbase = (lane >> 4) * 4;
    int cidx = lane & 15;
#pragma unroll
    for (int i = 0; i < 4; i++) {
#pragma unroll
        for (int j = 0; j < 4; j++) {
#pragma unroll
            for (int r = 0; r < 4; r++) {
                int row = m0 + wm * 64 + i * 16 + rbase + r;
                int col = n0 + wn * 64 + j * 16 + cidx;
                float v = acc[i][j][r];
                size_t idx = (size_t)row * N + col;
                if (MODE == 0) {
                    ((bf16*)Cv)[idx] = __float2bfloat16(v);
                } else if (MODE == 1) {
                    int h = col >> 6, kk = col & 63;
                    float outv = v;
                    if (rope) {
                        float other = __shfl_xor(v, 1);
                        float p = (float)(kk >> 1);
                        float theta = __expf(p * -0.5756462732485114f); // ln(1e4)/16
                        float ang = (float)row * theta;
                        float c, sn; __sincosf(ang, &sn, &c);
                        outv = (kk & 1) ? (v * c + other * sn) : (v * c - other * sn);
                    }
                    Cq[((size_t)h * 2048 + row) * 64 + kk] = __float2bfloat16(outv);
                } else if (MODE == 2) {
                    v += ((const float*)resv)[idx];
                    ((bf16*)Cv)[idx] = __float2bfloat16(v);
                } else if (MODE == 3) {
                    float u = __bfloat162float(((bf16*)Cv)[idx]);
                    float sg = 1.f / (1.f + __expf(-u));
                    ((bf16*)Cv)[idx] = __float2bfloat16(u * sg * v);
                } else {
                    v += __bfloat162float(((const bf16*)resv)[idx]);
                    ((float*)Cv)[idx] = v;
                }
            }
        }
    }
}

// ---------------------------------------------------------------------------
// MFMA causal flash attention (single batch). hd=64.
// q,k: [16][2048][64] bf16 (RoPE'd); vt: [16][64][2048] bf16 (V^T).
// Output o: [2048][1024] bf16 (concat heads).
//
// Rewritten (this round) for the latency/imbalance bottleneck:
//  - qt remap pairs heavy+light q-tiles on the same CU (b and b+256 share a
//    CU under XCD round-robin; old code put two equal-qt blocks there ->
//    2x makespan). Now each CU's pair sums to 33 iterations.
//  - Swapped QK^T: S^T = mfma(A=K, B=Q) puts col=q=lane&15 -> each lane owns
//    one q-row; softmax max/sum are in-lane + TWO shfl_xor (16,32) instead
//    of 32 dependent shuffles; m/l/alpha are per-lane scalars.
//  - log2-domain softmax (Q pre-scaled by 0.125*log2e, exp2 hw op).
//  - P^T exchanged through a wave-private LDS strip ([16 q][36 dwords],
//    b64 packed writes / b128 reads, bank-uniform) -> PV as O^T = V^T * P^T
//    with A-frags read straight from the V^T tile.
//  - Next K/V tile prefetched into registers AFTER the write barrier so HBM
//    latency hides under MFMA+softmax (old code exposed it between barriers).
//  - Epilogue transposes O^T via the same strip; global stores stay uint4.
// ---------------------------------------------------------------------------
__global__ __launch_bounds__(256) void attn_kernel(
    const bf16* __restrict__ q, const bf16* __restrict__ k,
    const bf16* __restrict__ vt, bf16* __restrict__ o)
{
    const int S = 2048;
    __shared__ bf16 Ks[64][72];
    __shared__ bf16 Vs[64][72];                        // V^T tile: [d][s]
    __shared__ __align__(16) char QPbuf[64 * 72 * 2];  // 9216 B; Q stage -> per-wave P/E strip

    int h = blockIdx.y;
    // Pair heavy with light on each CU: blocks b and b+256 (h and h+8) get
    // qt = 31-x and x -> per-CU work sums to 33 iters everywhere.
    int qt = (h & 8) ? (int)blockIdx.x : 31 - (int)blockIdx.x;
    int tid = threadIdx.x, lane = tid & 63, w = tid >> 6;
    int quad = lane >> 4, cidx = lane & 15;
    int m0 = qt * 64;

    const bf16* qb = q + ((size_t)h * S + m0) * 64;
    const bf16* kb = k + (size_t)h * S * 64;
    const bf16* vtb = vt + (size_t)h * 64 * S;

    int srow = tid >> 2;          // 0..63; wave w stages rows w*16..+15 (wave-private in QPbuf)
    int sg = (tid & 3) * 16;

    // ---- stage Q * (0.125 * log2e) into wave-private rows; hoist B-frags
    bf16 (*Qs)[72] = (bf16 (*)[72])QPbuf;
    {
        const uint4* src = (const uint4*)(qb + (size_t)srow * 64 + sg);
        uint4 u0 = src[0], u1 = src[1];
        float f[16]; unpack8(u0, f); unpack8(u1, f + 8);
#pragma unroll
        for (int i = 0; i < 16; i++) f[i] *= 0.125f * 1.44269504f;
        *(uint4*)&Qs[srow][sg] = packbf8(f);
        *(uint4*)&Qs[srow][sg + 8] = packbf8(f + 8);
    }
    // same-wave LDS write->read: DS pipe is in-order within a wave; no barrier
    bf16x8 bQ0 = *(const bf16x8*)&Qs[w * 16 + cidx][quad * 8];
    bf16x8 bQ1 = *(const bf16x8*)&Qs[w * 16 + cidx][32 + quad * 8];

    // wave-private strip [16 q][36 dwords] == exactly this wave's Q rows
    unsigned* Pst = (unsigned*)QPbuf + w * 576;

    float m_i = -INFINITY, l_i = 0.f;
    f32x4 Oc[4];
#pragma unroll
    for (int i = 0; i < 4; i++) Oc[i] = (f32x4){0.f, 0.f, 0.f, 0.f};

    // prefetch tile kt=0 into registers
    uint4 ka0, ka1, va0, va1;
    {
        const uint4* ksrc = (const uint4*)(kb + (size_t)srow * 64 + sg);
        ka0 = ksrc[0]; ka1 = ksrc[1];
        const uint4* vsrc = (const uint4*)(vtb + (size_t)srow * S + sg);
        va0 = vsrc[0]; va1 = vsrc[1];
    }

    for (int kt = 0; kt <= qt; kt++) {
        __syncthreads();          // all waves done reading previous K/V tile
        *(uint4*)&Ks[srow][sg] = ka0; *(uint4*)&Ks[srow][sg + 8] = ka1;
        *(uint4*)&Vs[srow][sg] = va0; *(uint4*)&Vs[srow][sg + 8] = va1;
        __syncthreads();
        if (kt < qt) {            // issue next tile's loads; latency hides under compute
            const uint4* kn = (const uint4*)(kb + (size_t)((kt + 1) * 64 + srow) * 64 + sg);
            ka0 = kn[0]; ka1 = kn[1];
            const uint4* vn = (const uint4*)(vtb + (size_t)srow * S + (kt + 1) * 64 + sg);
            va0 = vn[0]; va1 = vn[1];
        }

        // S^T tile: sc[i] holds S^T[kpos=i*16+quad*4+r][q=cidx] (log2 domain)
        f32x4 sc[4];
#pragma unroll
        for (int i = 0; i < 4; i++) {
            bf16x8 aK0 = *(const bf16x8*)&Ks[i * 16 + cidx][quad * 8];
            bf16x8 aK1 = *(const bf16x8*)&Ks[i * 16 + cidx][32 + quad * 8];
            f32x4 z = (f32x4){0.f, 0.f, 0.f, 0.f};
            z = __builtin_amdgcn_mfma_f32_16x16x32_bf16(aK0, bQ0, z, 0, 0, 0);
            z = __builtin_amdgcn_mfma_f32_16x16x32_bf16(aK1, bQ1, z, 0, 0, 0);
            sc[i] = z;
        }

        if (kt == qt) {           // causal mask: kpos > q
#pragma unroll
            for (int i = 0; i < 4; i++)
#pragma unroll
                for (int r = 0; r < 4; r++)
                    if (i * 16 + quad * 4 + r > w * 16 + cidx) sc[i][r] = -INFINITY;
        }

        // per-lane online softmax over k (lane owns q = w*16+cidx)
        float pmax = sc[0][0];
#pragma unroll
        for (int i = 0; i < 4; i++)
#pragma unroll
            for (int r = 0; r < 4; r++) pmax = fmaxf(pmax, sc[i][r]);
        pmax = fmaxf(pmax, __shfl_xor(pmax, 16));
        pmax = fmaxf(pmax, __shfl_xor(pmax, 32));
        float mnew = fmaxf(m_i, pmax);
        float alpha = __builtin_amdgcn_exp2f(m_i - mnew);
        float rs = 0.f;
#pragma unroll
        for (int i = 0; i < 4; i++)
#pragma unroll
            for (int r = 0; r < 4; r++) {
                sc[i][r] = __builtin_amdgcn_exp2f(sc[i][r] - mnew);
                rs += sc[i][r];
            }
        rs += __shfl_xor(rs, 16);
        rs += __shfl_xor(rs, 32);
        l_i = l_i * alpha + rs;
        m_i = mnew;
#pragma unroll
        for (int i = 0; i < 4; i++) {
            Oc[i][0] *= alpha; Oc[i][1] *= alpha;
            Oc[i][2] *= alpha; Oc[i][3] *= alpha;
        }

        // P^T -> wave-private strip (row=q, dword col=k/2); b64 packed writes
#pragma unroll
        for (int i = 0; i < 4; i++) {
            uint2 t;
            t.x = pack2(sc[i][0], sc[i][1]);
            t.y = pack2(sc[i][2], sc[i][3]);
            *(uint2*)&Pst[cidx * 36 + 8 * i + 2 * quad] = t;
        }
        bf16x8 bP0 = *(const bf16x8*)&Pst[cidx * 36 + 4 * quad];        // k 0..31
        bf16x8 bP1 = *(const bf16x8*)&Pst[cidx * 36 + 16 + 4 * quad];   // k 32..63

        // O^T += V^T * P^T  (A-frags straight from V^T tile)
#pragma unroll
        for (int i = 0; i < 4; i++) {
            bf16x8 aV0 = *(const bf16x8*)&Vs[i * 16 + cidx][quad * 8];
            bf16x8 aV1 = *(const bf16x8*)&Vs[i * 16 + cidx][32 + quad * 8];
            Oc[i] = __builtin_amdgcn_mfma_f32_16x16x32_bf16(aV0, bP0, Oc[i], 0, 0, 0);
            Oc[i] = __builtin_amdgcn_mfma_f32_16x16x32_bf16(aV1, bP1, Oc[i], 0, 0, 0);
        }
    }

    // epilogue: normalize, transpose O^T->O via wave-private strip, uint4 store
    float inv = 1.f / l_i;
#pragma unroll
    for (int i = 0; i < 4; i++) {
        uint2 t;
        t.x = pack2(Oc[i][0] * inv, Oc[i][1] * inv);
        t.y = pack2(Oc[i][2] * inv, Oc[i][3] * inv);
        *(uint2*)&Pst[cidx * 36 + 8 * i + 2 * quad] = t;
    }
    int r2 = lane >> 2, g2 = (lane & 3) * 8;     // row, dword col in strip
    uint4 o0 = *(const uint4*)&Pst[r2 * 36 + g2];
    uint4 o1 = *(const uint4*)&Pst[r2 * 36 + g2 + 4];
    bf16* orow = o + (size_t)(m0 + w * 16 + r2) * 1024 + h * 64;
    *(uint4*)(orow + g2 * 2) = o0;
    *(uint4*)(orow + g2 * 2 + 8) = o1;
}

// ---------------------------------------------------------------------------
extern "C" void kernel_launch(void* const* d_in, const int* in_sizes, int n_in,
                              void* d_out, int out_size, void* d_ws, size_t ws_size,
                              hipStream_t stream)
{
    const int S = 2048, D = 1024;

    const float* x    = (const float*)d_in[0];
    const float* ln1g = (const float*)d_in[1];
    const float* ln1b = (const float*)d_in[2];
    const float* Wq   = (const float*)d_in[3];
    const float* Wk   = (const float*)d_in[4];
    const float* Wv   = (const float*)d_in[5];
    const float* Wo   = (const float*)d_in[6];
    const float* ln2g = (const float*)d_in[7];
    const float* ln2b = (const float*)d_in[8];
    const float* W1   = (const float*)d_in[9];
    const float* W2   = (const float*)d_in[10];
    const float* W3   = (const float*)d_in[11];
    float* out = (float*)d_out;

    const size_t NR = (size_t)S * D;   // 2M elems per 4MB region
    bf16* r0 = (bf16*)d_ws;
    bf16* r1 = r0 + NR;
    bf16* r2 = r1 + NR;
    bf16* r3 = r2 + NR;
    const size_t M1 = 1u << 20;        // 1M elems

    for (int b = 0; b < 2; b++) {
        const float* xb = x + (size_t)b * S * D;
        float* ob = out + (size_t)b * S * D;   // 8 MB scratch / final out
        bf16* obB = (bf16*)ob;

        // 1. h = LN1(xb) -> r3
        ln_kernel<float, bf16><<<S, 256, 0, stream>>>(xb, ln1g, ln1b, r3);

        // 2. WqT/WkT/WvT -> obB[0:3M)
        tconv_kernel<<<dim3(2, 32, 16), 256, 0, stream>>>(Wq, obB,          1024, 64);
        tconv_kernel<<<dim3(2, 32, 16), 256, 0, stream>>>(Wk, obB + 1 * M1, 1024, 64);
        tconv_kernel<<<dim3(2, 32, 16), 256, 0, stream>>>(Wv, obB + 2 * M1, 1024, 64);

        // 3. q,k,v (+RoPE) -> r0,r1,r2
        mfma_gemm<1><<<dim3(8, 16, 3), 256, 0, stream>>>(r3, obB, r0, nullptr, S, 1024, 1024);

        // 4. V^T -> obB[0:2M)  (WqT/WkT dead)
        vtrans_kernel<<<dim3(32, 16), 256, 0, stream>>>(r2, obB);

        // 5. attn -> r2 (V natural dead)
        attn_kernel<<<dim3(32, 16), 256, 0, stream>>>(r0, r1, obB, r2);

        // 6. WoT -> obB[2M:3M) (WvT dead); x2 = xb + attn@Wo -> r3
        tconv_kernel<<<dim3(32, 32, 1), 256, 0, stream>>>(Wo, obB + 2 * M1, 1024, 1024);
        mfma_gemm<2><<<dim3(8, 16, 1), 256, 0, stream>>>(r2, obB + 2 * M1, r3, xb, S, 1024, 1024);

        // 7. h2 = LN2(r3) -> r0
        ln_kernel<bf16, bf16><<<S, 256, 0, stream>>>(r3, ln2g, ln2b, r0);

        // 8. W1T -> obB[0:2M) (Vt dead), W2T -> obB[2M:4M) (WoT dead)
        tconv_kernel<<<dim3(64, 32, 1), 256, 0, stream>>>(W1, obB,          1024, 2048);
        tconv_kernel<<<dim3(64, 32, 1), 256, 0, stream>>>(W2, obB + 2 * M1, 1024, 2048);

        // 9. u = h2 @ W1 -> r1 (spans r1..r2)
        mfma_gemm<0><<<dim3(16, 16, 1), 256, 0, stream>>>(r0, obB, r1, nullptr, S, 2048, 1024);

        // 10. sb = silu(u) * (h2 @ W2) -> r1 in-place
        mfma_gemm<3><<<dim3(16, 16, 1), 256, 0, stream>>>(r0, obB + 2 * M1, r1, nullptr, S, 2048, 1024);

        // 11. W3T -> r0 (h2 dead)
        tconv_kernel<<<dim3(32, 64, 1), 256, 0, stream>>>(W3, r0, 2048, 1024);

        // 12. out = x2 + sb @ W3 -> ob (fp32)
        mfma_gemm<4><<<dim3(8, 16, 1), 256, 0, stream>>>(r1, r0, ob, r3, S, 1024, 2048);
    }
}

// Round 2
// 410.023 us; speedup vs baseline: 1.5465x; 1.3669x over previous
//
#include <hip/hip_runtime.h>
#include <hip/hip_bf16.h>

using bf16 = __hip_bfloat16;
typedef __attribute__((ext_vector_type(8))) short bf16x8;
typedef __attribute__((ext_vector_type(4))) float f32x4;

// Shapes fixed: B=2, S=2048, D=1024, H=16, hd=64, F=2048.
// Global I/O fp32. Batches sequential. ws = 16 MB = 4 bf16 regions r0..r3
// (2M elems each). d_out half (8 MB) doubles as scratch (obB as bf16).
//
// Per-batch lifetimes (stream-ordered, audited):
//  1  LN1(xb)            -> r3
//  2  WqT/WkT/WvT        -> obB[0:1M)/[1M:2M)/[2M:3M)
//  3  QKV mfma (z=0,1,2) -> r0,r1,r2   (A=r3, B=obB+z*1M, rope z<2)
//  4  vtrans: r2 (V)     -> obB[0:2M)  (V^T [16][64][2048]; WqT/WkT dead)
//  5  attn(r0,r1,Vt=obB) -> r2         (V natural dead)
//  6  WoT -> obB[2M:3M) (WvT dead); mode2: A=r2, B=WoT, res=xb -> x2=r3
//  7  LN2(r3)            -> r0 (h2; q dead)
//  8  W1T -> obB[0:2M) (Vt dead), W2T -> obB[2M:4M) (WoT dead)
//  9  mode5 fused SwiGLU: A=r0, B1=W1T, B2=W2T -> sb = silu(u)*g -> r1
// 10  W3T -> r0 (h2 dead)
// 11  mode4: A=r1, B=r0(W3T), res=r3(x2) -> ob fp32 (final)

__device__ inline float toF(float x) { return x; }
__device__ inline float toF(bf16 x) { return __bfloat162float(x); }
__device__ inline void  stV(float* p, float v) { *p = v; }
__device__ inline void  stV(bf16* p, float v) { *p = __float2bfloat16(v); }

__device__ __forceinline__ void unpack8(uint4 u, float* f) {
    f[0] = __uint_as_float(u.x << 16); f[1] = __uint_as_float(u.x & 0xffff0000u);
    f[2] = __uint_as_float(u.y << 16); f[3] = __uint_as_float(u.y & 0xffff0000u);
    f[4] = __uint_as_float(u.z << 16); f[5] = __uint_as_float(u.z & 0xffff0000u);
    f[6] = __uint_as_float(u.w << 16); f[7] = __uint_as_float(u.w & 0xffff0000u);
}

__device__ __forceinline__ uint4 packbf8(const float* f) {
    union { unsigned short u[8]; uint4 v; } r;
#pragma unroll
    for (int i = 0; i < 8; i++) {
        bf16 b = __float2bfloat16(f[i]);
        r.u[i] = *(unsigned short*)&b;
    }
    return r.v;
}

__device__ __forceinline__ unsigned pack2(float lo, float hi) {
    bf16 a = __float2bfloat16(lo), b = __float2bfloat16(hi);
    return ((unsigned)*(unsigned short*)&b << 16) | (unsigned)*(unsigned short*)&a;
}

__device__ __forceinline__ void gl_lds16(const void* g, void* l) {
    __builtin_amdgcn_global_load_lds(
        (__attribute__((address_space(1))) void*)g,
        (__attribute__((address_space(3))) void*)l, 16, 0, 0);
}

// ---------------------------------------------------------------------------
// LayerNorm: one block per row, D=1024, 256 threads.
// ---------------------------------------------------------------------------
template <typename Tx, typename To>
__global__ __launch_bounds__(256) void ln_kernel(
    const Tx* __restrict__ x, const float* __restrict__ g,
    const float* __restrict__ b, To* __restrict__ out)
{
    const int D = 1024;
    int row = blockIdx.x;
    int tid = threadIdx.x;
    const Tx* xr = x + (size_t)row * D;

    float vals[4];
    float sum = 0.f, sumsq = 0.f;
#pragma unroll
    for (int i = 0; i < 4; i++) {
        float v = toF(xr[tid + i * 256]);
        vals[i] = v; sum += v; sumsq += v * v;
    }
#pragma unroll
    for (int off = 32; off > 0; off >>= 1) {
        sum += __shfl_xor(sum, off);
        sumsq += __shfl_xor(sumsq, off);
    }
    __shared__ float s1[4], s2[4];
    int wave = tid >> 6, lane = tid & 63;
    if (lane == 0) { s1[wave] = sum; s2[wave] = sumsq; }
    __syncthreads();
    sum = s1[0] + s1[1] + s1[2] + s1[3];
    sumsq = s2[0] + s2[1] + s2[2] + s2[3];

    float mu = sum * (1.f / D);
    float var = sumsq * (1.f / D) - mu * mu;
    float rstd = rsqrtf(var + 1e-5f);

    To* orow = out + (size_t)row * D;
#pragma unroll
    for (int i = 0; i < 4; i++) {
        int c = tid + i * 256;
        stV(&orow[c], (vals[i] - mu) * rstd * g[c] + b[c]);
    }
}

// ---------------------------------------------------------------------------
// Transpose+convert: in fp32 [R][C] (per z-slice) -> out bf16 [C][R].
// ---------------------------------------------------------------------------
__global__ __launch_bounds__(256) void tconv_kernel(
    const float* __restrict__ in, bf16* __restrict__ out, int R, int C)
{
    __shared__ float t[32][33];
    int hh = blockIdx.z;
    const float* ip = in + (size_t)hh * R * C;
    bf16* op = out + (size_t)hh * R * C;
    int c0 = blockIdx.x * 32, r0 = blockIdx.y * 32;
    int tx = threadIdx.x & 31, ty = threadIdx.x >> 5;  // ty 0..7
#pragma unroll
    for (int i = 0; i < 4; i++)
        t[ty + 8 * i][tx] = ip[(size_t)(r0 + ty + 8 * i) * C + c0 + tx];
    __syncthreads();
#pragma unroll
    for (int i = 0; i < 4; i++)
        op[(size_t)(c0 + ty + 8 * i) * R + r0 + tx] = __float2bfloat16(t[tx][ty + 8 * i]);
}

// ---------------------------------------------------------------------------
// V transpose (bf16): v [16][2048][64] -> vt [16][64][2048]. 64x64 tiles.
// ---------------------------------------------------------------------------
__global__ __launch_bounds__(256) void vtrans_kernel(
    const bf16* __restrict__ v, bf16* __restrict__ vt)
{
    __shared__ unsigned short t[64][68];
    int hh = blockIdx.y;
    int s0 = blockIdx.x * 64;
    int tid = threadIdx.x;
    int r = tid >> 2, g = (tid & 3) * 16;

    const uint4* src = (const uint4*)(v + ((size_t)hh * 2048 + s0 + r) * 64 + g);
    *(uint4*)&t[r][g] = src[0];
    *(uint4*)&t[r][g + 8] = src[1];
    __syncthreads();

    union { unsigned short u[16]; uint4 v4[2]; } o;
#pragma unroll
    for (int i = 0; i < 16; i++) o.u[i] = t[g + i][r];
    uint4* dst = (uint4*)(vt + ((size_t)hh * 64 + r) * 2048 + s0 + g);
    dst[0] = o.v4[0];
    dst[1] = o.v4[1];
}

// ---------------------------------------------------------------------------
// MFMA GEMM: C[M,N] = A[M,K](bf16) @ B (BT[N,K] bf16), fp32 accum.
// 128x128 tile, BK=64, 4 waves (2x2), 4x4 16x16 MFMA subtiles per wave.
//
// This round (latency-bound at 1 block/CU, MfmaUtil 6%, 1.05M bank-conflicts):
//  - 2-phase double-buffered K-loop: next tile's global_load_lds issued
//    BEFORE the current tile's ds_read+MFMA; the per-step __syncthreads
//    (which drains vmcnt) lands after ~350cyc of compute, hiding load
//    latency that was previously fully exposed (no TLP at 1 wave/SIMD).
//  - BK=64: halves the number of latency-exposed barrier points. LDS =
//    2buf x (A+B) x 16KB = 64KB (occupancy is grid-limited anyway).
//  - T2 XOR swizzle: physical 16B slot = logical ^ (row&7). gl_lds writes
//    linearly, so the swizzle is applied on the global SOURCE address
//    (lcb = (lane&7)^(lane>>3)) and mirrored on the ds_read side ->
//    ds_read_b128 becomes 2 lanes/bank (free) instead of 8-way.
//
// MODE 1: QKV scatter [H][S][64] + RoPE (z selects B/C; rope for z<2)
// MODE 2: C bf16 = acc + resF32
// MODE 4: C f32  = acc + resBf16
// MODE 5: fused SwiGLU: two K-passes (B1=BT0, B2=resv);
//         C bf16 = silu(acc1) * acc2
// ---------------------------------------------------------------------------
template <int MODE>
__global__ __launch_bounds__(256) void mfma_gemm(
    const bf16* __restrict__ A, const bf16* __restrict__ BT0,
    void* __restrict__ Cv, const void* __restrict__ resv,
    int M, int N, int K)
{
    __shared__ bf16 smem[2][2][128 * 64];   // [buf][A/B][row*64 + col], 64KB
    int tid = threadIdx.x, lane = tid & 63, w = tid >> 6;
    int wm = w >> 1, wn = w & 1;
    int m0 = blockIdx.y * 128, n0 = blockIdx.x * 128;

    const bf16* BT = BT0;
    bf16* Cq = nullptr; int rope = 0;
    if (MODE == 1) {
        int z = blockIdx.z;
        BT = BT0 + ((size_t)z << 20);
        Cq = (bf16*)Cv + ((size_t)z << 21);
        rope = (z < 2);
    }

    // staging: lane covers row w*8 + (lane>>3) (+32 per issue),
    // global col-block pre-swizzled so linear LDS write == swizzled layout
    int lrow = lane >> 3;                  // 0..7
    int lcb  = (lane & 7) ^ lrow;          // pre-swizzled 16B col-block
    const bf16* Ag  = A  + (size_t)(m0 + w * 8 + lrow) * K + lcb * 8;
    const bf16* Bg0 = BT + (size_t)(n0 + w * 8 + lrow) * K + lcb * 8;
    unsigned sbase = (unsigned)__builtin_amdgcn_readfirstlane(w * 8 * 128);
    char* smc = (char*)smem;

    f32x4 acc[4][4], acc2[4][4];
#pragma unroll
    for (int i = 0; i < 4; i++)
#pragma unroll
        for (int j = 0; j < 4; j++) {
            acc[i][j] = (f32x4){0.f, 0.f, 0.f, 0.f};
            acc2[i][j] = (f32x4){0.f, 0.f, 0.f, 0.f};
        }

    int cidx = lane & 15, quad = lane >> 4;

    auto run_pass = [&](const bf16* Bg, f32x4 (&ac)[4][4]) {
        auto STAGE = [&](int buf, int k0) {
            char* pA = smc + (size_t)buf * 32768 + sbase;
            char* pB = pA + 16384;
#pragma unroll
            for (int n = 0; n < 4; n++) {
                gl_lds16(Ag + (size_t)(n * 32) * K + k0, pA + n * 32 * 128);
                gl_lds16(Bg + (size_t)(n * 32) * K + k0, pB + n * 32 * 128);
            }
        };
        STAGE(0, 0);
        __syncthreads();                 // drains vmcnt, publishes buf0
        int cur = 0;
        for (int k0 = 0; k0 < K; k0 += 64) {
            if (k0 + 64 < K) STAGE(cur ^ 1, k0 + 64);   // prefetch next
            const bf16* Ab = (const bf16*)(smc + (size_t)cur * 32768);
            const bf16* Bb = Ab + 8192;
#pragma unroll
            for (int kk = 0; kk < 2; kk++) {
                int pb = (kk * 4 + quad) ^ (cidx & 7);  // swizzled slot
                bf16x8 af[4], bfr[4];
#pragma unroll
                for (int i = 0; i < 4; i++)
                    af[i] = *(const bf16x8*)&Ab[(wm * 64 + i * 16 + cidx) * 64 + pb * 8];
#pragma unroll
                for (int j = 0; j < 4; j++)
                    bfr[j] = *(const bf16x8*)&Bb[(wn * 64 + j * 16 + cidx) * 64 + pb * 8];
#pragma unroll
                for (int i = 0; i < 4; i++)
#pragma unroll
                    for (int j = 0; j < 4; j++)
                        ac[i][j] = __builtin_amdgcn_mfma_f32_16x16x32_bf16(af[i], bfr[j], ac[i][j], 0, 0, 0);
            }
            __syncthreads();             // reads of cur done + prefetch landed
            cur ^= 1;
        }
    };

    run_pass(Bg0, acc);
    if (MODE == 5) {
        const bf16* B2g = (const bf16*)resv + (size_t)(n0 + w * 8 + lrow) * K + lcb * 8;
        run_pass(B2g, acc2);
    }

    int rbase = quad * 4;
#pragma unroll
    for (int i = 0; i < 4; i++) {
#pragma unroll
        for (int j = 0; j < 4; j++) {
#pragma unroll
            for (int r = 0; r < 4; r++) {
                int row = m0 + wm * 64 + i * 16 + rbase + r;
                int col = n0 + wn * 64 + j * 16 + cidx;
                float v = acc[i][j][r];
                size_t idx = (size_t)row * N + col;
                if (MODE == 1) {
                    int h = col >> 6, kk = col & 63;
                    float outv = v;
                    if (rope) {
                        float other = __shfl_xor(v, 1);
                        float p = (float)(kk >> 1);
                        float theta = __expf(p * -0.5756462732485114f); // ln(1e4)/16
                        float ang = (float)row * theta;
                        float c, sn; __sincosf(ang, &sn, &c);
                        outv = (kk & 1) ? (v * c + other * sn) : (v * c - other * sn);
                    }
                    Cq[((size_t)h * 2048 + row) * 64 + kk] = __float2bfloat16(outv);
                } else if (MODE == 2) {
                    v += ((const float*)resv)[idx];
                    ((bf16*)Cv)[idx] = __float2bfloat16(v);
                } else if (MODE == 5) {
                    float g2 = acc2[i][j][r];
                    float sg = 1.f / (1.f + __expf(-v));
                    ((bf16*)Cv)[idx] = __float2bfloat16(v * sg * g2);
                } else {
                    v += __bfloat162float(((const bf16*)resv)[idx]);
                    ((float*)Cv)[idx] = v;
                }
            }
        }
    }
}

// ---------------------------------------------------------------------------
// MFMA causal flash attention (single batch). hd=64.
// q,k: [16][2048][64] bf16 (RoPE'd); vt: [16][64][2048] bf16 (V^T).
// Output o: [2048][1024] bf16 (concat heads).
//  - qt remap pairs heavy+light q-tiles on the same CU.
//  - Swapped QK^T (S^T = K*Q): lane owns one q-row; softmax in-lane + 2 shfl.
//  - log2-domain softmax (Q pre-scaled by 0.125*log2e, exp2 hw op).
//  - P^T via wave-private LDS strip (b64 writes / b128 reads, bank-uniform).
//  - Next K/V tile prefetched into registers after the write barrier.
// ---------------------------------------------------------------------------
__global__ __launch_bounds__(256) void attn_kernel(
    const bf16* __restrict__ q, const bf16* __restrict__ k,
    const bf16* __restrict__ vt, bf16* __restrict__ o)
{
    const int S = 2048;
    __shared__ bf16 Ks[64][72];
    __shared__ bf16 Vs[64][72];                        // V^T tile: [d][s]
    __shared__ __align__(16) char QPbuf[64 * 72 * 2];  // Q stage -> per-wave P strip

    int h = blockIdx.y;
    int qt = (h & 8) ? (int)blockIdx.x : 31 - (int)blockIdx.x;
    int tid = threadIdx.x, lane = tid & 63, w = tid >> 6;
    int quad = lane >> 4, cidx = lane & 15;
    int m0 = qt * 64;

    const bf16* qb = q + ((size_t)h * S + m0) * 64;
    const bf16* kb = k + (size_t)h * S * 64;
    const bf16* vtb = vt + (size_t)h * 64 * S;

    int srow = tid >> 2;
    int sg = (tid & 3) * 16;

    bf16 (*Qs)[72] = (bf16 (*)[72])QPbuf;
    {
        const uint4* src = (const uint4*)(qb + (size_t)srow * 64 + sg);
        uint4 u0 = src[0], u1 = src[1];
        float f[16]; unpack8(u0, f); unpack8(u1, f + 8);
#pragma unroll
        for (int i = 0; i < 16; i++) f[i] *= 0.125f * 1.44269504f;
        *(uint4*)&Qs[srow][sg] = packbf8(f);
        *(uint4*)&Qs[srow][sg + 8] = packbf8(f + 8);
    }
    bf16x8 bQ0 = *(const bf16x8*)&Qs[w * 16 + cidx][quad * 8];
    bf16x8 bQ1 = *(const bf16x8*)&Qs[w * 16 + cidx][32 + quad * 8];

    unsigned* Pst = (unsigned*)QPbuf + w * 576;

    float m_i = -INFINITY, l_i = 0.f;
    f32x4 Oc[4];
#pragma unroll
    for (int i = 0; i < 4; i++) Oc[i] = (f32x4){0.f, 0.f, 0.f, 0.f};

    uint4 ka0, ka1, va0, va1;
    {
        const uint4* ksrc = (const uint4*)(kb + (size_t)srow * 64 + sg);
        ka0 = ksrc[0]; ka1 = ksrc[1];
        const uint4* vsrc = (const uint4*)(vtb + (size_t)srow * S + sg);
        va0 = vsrc[0]; va1 = vsrc[1];
    }

    for (int kt = 0; kt <= qt; kt++) {
        __syncthreads();
        *(uint4*)&Ks[srow][sg] = ka0; *(uint4*)&Ks[srow][sg + 8] = ka1;
        *(uint4*)&Vs[srow][sg] = va0; *(uint4*)&Vs[srow][sg + 8] = va1;
        __syncthreads();
        if (kt < qt) {
            const uint4* kn = (const uint4*)(kb + (size_t)((kt + 1) * 64 + srow) * 64 + sg);
            ka0 = kn[0]; ka1 = kn[1];
            const uint4* vn = (const uint4*)(vtb + (size_t)srow * S + (kt + 1) * 64 + sg);
            va0 = vn[0]; va1 = vn[1];
        }

        f32x4 sc[4];
#pragma unroll
        for (int i = 0; i < 4; i++) {
            bf16x8 aK0 = *(const bf16x8*)&Ks[i * 16 + cidx][quad * 8];
            bf16x8 aK1 = *(const bf16x8*)&Ks[i * 16 + cidx][32 + quad * 8];
            f32x4 z = (f32x4){0.f, 0.f, 0.f, 0.f};
            z = __builtin_amdgcn_mfma_f32_16x16x32_bf16(aK0, bQ0, z, 0, 0, 0);
            z = __builtin_amdgcn_mfma_f32_16x16x32_bf16(aK1, bQ1, z, 0, 0, 0);
            sc[i] = z;
        }

        if (kt == qt) {
#pragma unroll
            for (int i = 0; i < 4; i++)
#pragma unroll
                for (int r = 0; r < 4; r++)
                    if (i * 16 + quad * 4 + r > w * 16 + cidx) sc[i][r] = -INFINITY;
        }

        float pmax = sc[0][0];
#pragma unroll
        for (int i = 0; i < 4; i++)
#pragma unroll
            for (int r = 0; r < 4; r++) pmax = fmaxf(pmax, sc[i][r]);
        pmax = fmaxf(pmax, __shfl_xor(pmax, 16));
        pmax = fmaxf(pmax, __shfl_xor(pmax, 32));
        float mnew = fmaxf(m_i, pmax);
        float alpha = __builtin_amdgcn_exp2f(m_i - mnew);
        float rs = 0.f;
#pragma unroll
        for (int i = 0; i < 4; i++)
#pragma unroll
            for (int r = 0; r < 4; r++) {
                sc[i][r] = __builtin_amdgcn_exp2f(sc[i][r] - mnew);
                rs += sc[i][r];
            }
        rs += __shfl_xor(rs, 16);
        rs += __shfl_xor(rs, 32);
        l_i = l_i * alpha + rs;
        m_i = mnew;
#pragma unroll
        for (int i = 0; i < 4; i++) {
            Oc[i][0] *= alpha; Oc[i][1] *= alpha;
            Oc[i][2] *= alpha; Oc[i][3] *= alpha;
        }

#pragma unroll
        for (int i = 0; i < 4; i++) {
            uint2 t;
            t.x = pack2(sc[i][0], sc[i][1]);
            t.y = pack2(sc[i][2], sc[i][3]);
            *(uint2*)&Pst[cidx * 36 + 8 * i + 2 * quad] = t;
        }
        bf16x8 bP0 = *(const bf16x8*)&Pst[cidx * 36 + 4 * quad];
        bf16x8 bP1 = *(const bf16x8*)&Pst[cidx * 36 + 16 + 4 * quad];

#pragma unroll
        for (int i = 0; i < 4; i++) {
            bf16x8 aV0 = *(const bf16x8*)&Vs[i * 16 + cidx][quad * 8];
            bf16x8 aV1 = *(const bf16x8*)&Vs[i * 16 + cidx][32 + quad * 8];
            Oc[i] = __builtin_amdgcn_mfma_f32_16x16x32_bf16(aV0, bP0, Oc[i], 0, 0, 0);
            Oc[i] = __builtin_amdgcn_mfma_f32_16x16x32_bf16(aV1, bP1, Oc[i], 0, 0, 0);
        }
    }

    float inv = 1.f / l_i;
#pragma unroll
    for (int i = 0; i < 4; i++) {
        uint2 t;
        t.x = pack2(Oc[i][0] * inv, Oc[i][1] * inv);
        t.y = pack2(Oc[i][2] * inv, Oc[i][3] * inv);
        *(uint2*)&Pst[cidx * 36 + 8 * i + 2 * quad] = t;
    }
    int r2 = lane >> 2, g2 = (lane & 3) * 8;
    uint4 o0 = *(const uint4*)&Pst[r2 * 36 + g2];
    uint4 o1 = *(const uint4*)&Pst[r2 * 36 + g2 + 4];
    bf16* orow = o + (size_t)(m0 + w * 16 + r2) * 1024 + h * 64;
    *(uint4*)(orow + g2 * 2) = o0;
    *(uint4*)(orow + g2 * 2 + 8) = o1;
}

// ---------------------------------------------------------------------------
extern "C" void kernel_launch(void* const* d_in, const int* in_sizes, int n_in,
                              void* d_out, int out_size, void* d_ws, size_t ws_size,
                              hipStream_t stream)
{
    const int S = 2048, D = 1024;

    const float* x    = (const float*)d_in[0];
    const float* ln1g = (const float*)d_in[1];
    const float* ln1b = (const float*)d_in[2];
    const float* Wq   = (const float*)d_in[3];
    const float* Wk   = (const float*)d_in[4];
    const float* Wv   = (const float*)d_in[5];
    const float* Wo   = (const float*)d_in[6];
    const float* ln2g = (const float*)d_in[7];
    const float* ln2b = (const float*)d_in[8];
    const float* W1   = (const float*)d_in[9];
    const float* W2   = (const float*)d_in[10];
    const float* W3   = (const float*)d_in[11];
    float* out = (float*)d_out;

    const size_t NR = (size_t)S * D;   // 2M elems per 4MB region
    bf16* r0 = (bf16*)d_ws;
    bf16* r1 = r0 + NR;
    bf16* r2 = r1 + NR;
    bf16* r3 = r2 + NR;
    const size_t M1 = 1u << 20;        // 1M elems

    for (int b = 0; b < 2; b++) {
        const float* xb = x + (size_t)b * S * D;
        float* ob = out + (size_t)b * S * D;   // 8 MB scratch / final out
        bf16* obB = (bf16*)ob;

        // 1. h = LN1(xb) -> r3
        ln_kernel<float, bf16><<<S, 256, 0, stream>>>(xb, ln1g, ln1b, r3);

        // 2. WqT/WkT/WvT -> obB[0:3M)
        tconv_kernel<<<dim3(2, 32, 16), 256, 0, stream>>>(Wq, obB,          1024, 64);
        tconv_kernel<<<dim3(2, 32, 16), 256, 0, stream>>>(Wk, obB + 1 * M1, 1024, 64);
        tconv_kernel<<<dim3(2, 32, 16), 256, 0, stream>>>(Wv, obB + 2 * M1, 1024, 64);

        // 3. q,k,v (+RoPE) -> r0,r1,r2
        mfma_gemm<1><<<dim3(8, 16, 3), 256, 0, stream>>>(r3, obB, r0, nullptr, S, 1024, 1024);

        // 4. V^T -> obB[0:2M)  (WqT/WkT dead)
        vtrans_kernel<<<dim3(32, 16), 256, 0, stream>>>(r2, obB);

        // 5. attn -> r2 (V natural dead)
        attn_kernel<<<dim3(32, 16), 256, 0, stream>>>(r0, r1, obB, r2);

        // 6. WoT -> obB[2M:3M) (WvT dead); x2 = xb + attn@Wo -> r3
        tconv_kernel<<<dim3(32, 32, 1), 256, 0, stream>>>(Wo, obB + 2 * M1, 1024, 1024);
        mfma_gemm<2><<<dim3(8, 16, 1), 256, 0, stream>>>(r2, obB + 2 * M1, r3, xb, S, 1024, 1024);

        // 7. h2 = LN2(r3) -> r0
        ln_kernel<bf16, bf16><<<S, 256, 0, stream>>>(r3, ln2g, ln2b, r0);

        // 8. W1T -> obB[0:2M) (Vt dead), W2T -> obB[2M:4M) (WoT dead)
        tconv_kernel<<<dim3(64, 32, 1), 256, 0, stream>>>(W1, obB,          1024, 2048);
        tconv_kernel<<<dim3(64, 32, 1), 256, 0, stream>>>(W2, obB + 2 * M1, 1024, 2048);

        // 9. sb = silu(h2@W1) * (h2@W2) -> r1 (spans r1..r2)  [fused SwiGLU]
        mfma_gemm<5><<<dim3(16, 16, 1), 256, 0, stream>>>(r0, obB, r1, obB + 2 * M1, S, 2048, 1024);

        // 10. W3T -> r0 (h2 dead)
        tconv_kernel<<<dim3(32, 64, 1), 256, 0, stream>>>(W3, r0, 2048, 1024);

        // 11. out = x2 + sb @ W3 -> ob (fp32)
        mfma_gemm<4><<<dim3(8, 16, 1), 256, 0, stream>>>(r1, r0, ob, r3, S, 1024, 2048);
    }
}

// Round 3
// 382.157 us; speedup vs baseline: 1.6592x; 1.0729x over previous
//
#include <hip/hip_runtime.h>
#include <hip/hip_bf16.h>

using bf16 = __hip_bfloat16;
typedef __attribute__((ext_vector_type(8))) short bf16x8;
typedef __attribute__((ext_vector_type(4))) float f32x4;

// Shapes fixed: B=2, S=2048, D=1024, H=16, hd=64, F=2048.
// Global I/O fp32. Batches sequential. ws = 16 MB = 4 bf16 regions r0..r3
// (2M elems each). d_out half (8 MB) doubles as scratch (obB as bf16).
//
// Per-batch lifetimes (stream-ordered, audited):
//  1  LN1(xb)            -> r3
//  2  WqT/WkT/WvT        -> obB[0:1M)/[1M:2M)/[2M:3M)   (one tconv3 dispatch)
//  3  QKV mfma (z=0,1,2) -> r0,r1,r2   (A=r3, B=obB+z*1M, rope z<2)
//  4  vtrans: r2 (V)     -> obB[0:2M)  (V^T [16][64][2048]; WqT/WkT dead)
//  5  attn(r0,r1,Vt=obB) -> r2         (V natural dead)
//  6  WoT -> obB[2M:3M) (WvT dead); mode2: A=r2, B=WoT, res=xb -> x2=r3
//  7  LN2(r3)            -> r0 (h2; q dead)
//  8  W1T -> obB[0:2M) (Vt dead), W2T -> obB[2M:4M) (WoT dead)
//  9  mode5 fused SwiGLU: A=r0, B1=W1T, B2=W2T -> sb = silu(u)*g -> r1
// 10  W3T -> r0 (h2 dead)
// 11  mode4: A=r1, B=r0(W3T), res=r3(x2) -> ob fp32 (final)

__device__ inline float toF(float x) { return x; }
__device__ inline float toF(bf16 x) { return __bfloat162float(x); }
__device__ inline void  stV(float* p, float v) { *p = v; }
__device__ inline void  stV(bf16* p, float v) { *p = __float2bfloat16(v); }

__device__ __forceinline__ void unpack8(uint4 u, float* f) {
    f[0] = __uint_as_float(u.x << 16); f[1] = __uint_as_float(u.x & 0xffff0000u);
    f[2] = __uint_as_float(u.y << 16); f[3] = __uint_as_float(u.y & 0xffff0000u);
    f[4] = __uint_as_float(u.z << 16); f[5] = __uint_as_float(u.z & 0xffff0000u);
    f[6] = __uint_as_float(u.w << 16); f[7] = __uint_as_float(u.w & 0xffff0000u);
}

__device__ __forceinline__ uint4 packbf8(const float* f) {
    union { unsigned short u[8]; uint4 v; } r;
#pragma unroll
    for (int i = 0; i < 8; i++) {
        bf16 b = __float2bfloat16(f[i]);
        r.u[i] = *(unsigned short*)&b;
    }
    return r.v;
}

__device__ __forceinline__ unsigned pack2(float lo, float hi) {
    bf16 a = __float2bfloat16(lo), b = __float2bfloat16(hi);
    return ((unsigned)*(unsigned short*)&b << 16) | (unsigned)*(unsigned short*)&a;
}

__device__ __forceinline__ void gl_lds16(const void* g, void* l) {
    __builtin_amdgcn_global_load_lds(
        (__attribute__((address_space(1))) void*)g,
        (__attribute__((address_space(3))) void*)l, 16, 0, 0);
}

// ---------------------------------------------------------------------------
// LayerNorm: one block per row, D=1024, 256 threads.
// ---------------------------------------------------------------------------
template <typename Tx, typename To>
__global__ __launch_bounds__(256) void ln_kernel(
    const Tx* __restrict__ x, const float* __restrict__ g,
    const float* __restrict__ b, To* __restrict__ out)
{
    const int D = 1024;
    int row = blockIdx.x;
    int tid = threadIdx.x;
    const Tx* xr = x + (size_t)row * D;

    float vals[4];
    float sum = 0.f, sumsq = 0.f;
#pragma unroll
    for (int i = 0; i < 4; i++) {
        float v = toF(xr[tid + i * 256]);
        vals[i] = v; sum += v; sumsq += v * v;
    }
#pragma unroll
    for (int off = 32; off > 0; off >>= 1) {
        sum += __shfl_xor(sum, off);
        sumsq += __shfl_xor(sumsq, off);
    }
    __shared__ float s1[4], s2[4];
    int wave = tid >> 6, lane = tid & 63;
    if (lane == 0) { s1[wave] = sum; s2[wave] = sumsq; }
    __syncthreads();
    sum = s1[0] + s1[1] + s1[2] + s1[3];
    sumsq = s2[0] + s2[1] + s2[2] + s2[3];

    float mu = sum * (1.f / D);
    float var = sumsq * (1.f / D) - mu * mu;
    float rstd = rsqrtf(var + 1e-5f);

    To* orow = out + (size_t)row * D;
#pragma unroll
    for (int i = 0; i < 4; i++) {
        int c = tid + i * 256;
        stV(&orow[c], (vals[i] - mu) * rstd * g[c] + b[c]);
    }
}

// ---------------------------------------------------------------------------
// Transpose+convert: in fp32 [R][C] (per z-slice) -> out bf16 [C][R].
// ---------------------------------------------------------------------------
__global__ __launch_bounds__(256) void tconv_kernel(
    const float* __restrict__ in, bf16* __restrict__ out, int R, int C)
{
    __shared__ float t[32][33];
    int hh = blockIdx.z;
    const float* ip = in + (size_t)hh * R * C;
    bf16* op = out + (size_t)hh * R * C;
    int c0 = blockIdx.x * 32, r0 = blockIdx.y * 32;
    int tx = threadIdx.x & 31, ty = threadIdx.x >> 5;  // ty 0..7
#pragma unroll
    for (int i = 0; i < 4; i++)
        t[ty + 8 * i][tx] = ip[(size_t)(r0 + ty + 8 * i) * C + c0 + tx];
    __syncthreads();
#pragma unroll
    for (int i = 0; i < 4; i++)
        op[(size_t)(c0 + ty + 8 * i) * R + r0 + tx] = __float2bfloat16(t[tx][ty + 8 * i]);
}

// Fused Wq/Wk/Wv transpose: z in [0,48), slice z&15 of source z>>4.
// Each source [16][1024][64] fp32 -> out bf16 [z>>4 * 1M + (z&15)*64K) [64][1024].
__global__ __launch_bounds__(256) void tconv3_kernel(
    const float* __restrict__ Aq, const float* __restrict__ Ak,
    const float* __restrict__ Av, bf16* __restrict__ out)
{
    __shared__ float t[32][33];
    int z = blockIdx.z;
    const float* in = (z < 16) ? Aq : (z < 32) ? Ak : Av;
    int hh = z & 15;
    const float* ip = in + (size_t)hh * 65536;
    bf16* op = out + ((size_t)(z >> 4) << 20) + (size_t)hh * 65536;
    int c0 = blockIdx.x * 32, r0 = blockIdx.y * 32;
    int tx = threadIdx.x & 31, ty = threadIdx.x >> 5;
#pragma unroll
    for (int i = 0; i < 4; i++)
        t[ty + 8 * i][tx] = ip[(size_t)(r0 + ty + 8 * i) * 64 + c0 + tx];
    __syncthreads();
#pragma unroll
    for (int i = 0; i < 4; i++)
        op[(size_t)(c0 + ty + 8 * i) * 1024 + r0 + tx] = __float2bfloat16(t[tx][ty + 8 * i]);
}

// ---------------------------------------------------------------------------
// V transpose (bf16): v [16][2048][64] -> vt [16][64][2048]. 64x64 tiles.
// ---------------------------------------------------------------------------
__global__ __launch_bounds__(256) void vtrans_kernel(
    const bf16* __restrict__ v, bf16* __restrict__ vt)
{
    __shared__ unsigned short t[64][68];
    int hh = blockIdx.y;
    int s0 = blockIdx.x * 64;
    int tid = threadIdx.x;
    int r = tid >> 2, g = (tid & 3) * 16;

    const uint4* src = (const uint4*)(v + ((size_t)hh * 2048 + s0 + r) * 64 + g);
    *(uint4*)&t[r][g] = src[0];
    *(uint4*)&t[r][g + 8] = src[1];
    __syncthreads();

    union { unsigned short u[16]; uint4 v4[2]; } o;
#pragma unroll
    for (int i = 0; i < 16; i++) o.u[i] = t[g + i][r];
    uint4* dst = (uint4*)(vt + ((size_t)hh * 64 + r) * 2048 + s0 + g);
    dst[0] = o.v4[0];
    dst[1] = o.v4[1];
}

// ---------------------------------------------------------------------------
// MFMA GEMM: C[M,N] = A[M,K](bf16) @ B (BT[N,K] bf16), fp32 accum.
//
// This round: tile 64x64 (was 128x128) -- the GEMMs were occupancy-starved
// (mode2/4: 128 blocks on 256 CUs = half idle; mode5: 1 block/CU = 1
// wave/SIMD, so the per-step barrier vmcnt-drain was fully exposed).
// 64x64 -> grids 512..1536 blocks (2-6 blocks/CU); other blocks' compute
// covers each block's barrier drain. LDS 32KB/block (5 blocks/CU cap).
// 4 waves (2x2), wave tile 32x32 = 2x2 16x16 subtiles, BK=64 double-buffer,
// source-pre-swizzled LDS (conflict-free ds_read_b128), setprio around MFMA.
//
// MODE 1: QKV scatter [H][S][64] + RoPE (z selects B/C; rope for z<2)
// MODE 2: C bf16 = acc + resF32
// MODE 4: C f32  = acc + resBf16
// MODE 5: fused SwiGLU: two K-passes (B1=BT0, B2=resv); C bf16 = silu(u)*g
// ---------------------------------------------------------------------------
template <int MODE>
__global__ __launch_bounds__(256) void mfma_gemm(
    const bf16* __restrict__ A, const bf16* __restrict__ BT0,
    void* __restrict__ Cv, const void* __restrict__ resv,
    int M, int N, int K)
{
    __shared__ bf16 smem[2][2][64 * 64];   // [buf][A/B][row*64+col], 32KB
    int tid = threadIdx.x, lane = tid & 63, w = tid >> 6;
    int wm = w >> 1, wn = w & 1;
    int m0 = blockIdx.y * 64, n0 = blockIdx.x * 64;

    const bf16* BT = BT0;
    bf16* Cq = nullptr; int rope = 0;
    if (MODE == 1) {
        int z = blockIdx.z;
        BT = BT0 + ((size_t)z << 20);
        Cq = (bf16*)Cv + ((size_t)z << 21);
        rope = (z < 2);
    }

    // staging: wave w covers rows w*8+lrow and +32; 16B col-block
    // pre-swizzled on the GLOBAL source so linear LDS write == swizzled layout
    int lrow = lane >> 3;                  // 0..7
    int lcb  = (lane & 7) ^ lrow;          // pre-swizzled 16B col-block
    const bf16* Ag  = A  + (size_t)(m0 + w * 8 + lrow) * K + lcb * 8;
    const bf16* Bg0 = BT + (size_t)(n0 + w * 8 + lrow) * K + lcb * 8;
    unsigned sbase = (unsigned)__builtin_amdgcn_readfirstlane(w * 8 * 128);
    char* smc = (char*)smem;

    f32x4 acc[2][2], acc2[2][2];
#pragma unroll
    for (int i = 0; i < 2; i++)
#pragma unroll
        for (int j = 0; j < 2; j++) {
            acc[i][j] = (f32x4){0.f, 0.f, 0.f, 0.f};
            if (MODE == 5) acc2[i][j] = (f32x4){0.f, 0.f, 0.f, 0.f};
        }

    int cidx = lane & 15, quad = lane >> 4;

    auto run_pass = [&](const bf16* Bg, f32x4 (&ac)[2][2]) {
        auto STAGE = [&](int buf, int k0) {
            char* pA = smc + (size_t)buf * 16384 + sbase;
            char* pB = pA + 8192;
            gl_lds16(Ag + k0,                  pA);
            gl_lds16(Ag + (size_t)32 * K + k0, pA + 4096);
            gl_lds16(Bg + k0,                  pB);
            gl_lds16(Bg + (size_t)32 * K + k0, pB + 4096);
        };
        STAGE(0, 0);
        __syncthreads();                 // drains vmcnt, publishes buf0
        int cur = 0;
        for (int k0 = 0; k0 < K; k0 += 64) {
            if (k0 + 64 < K) STAGE(cur ^ 1, k0 + 64);   // prefetch next
            const bf16* Ab = (const bf16*)(smc + (size_t)cur * 16384);
            const bf16* Bb = Ab + 4096;
#pragma unroll
            for (int kk = 0; kk < 2; kk++) {
                int pb = (kk * 4 + quad) ^ (cidx & 7);  // swizzled slot
                bf16x8 af[2], bfr[2];
#pragma unroll
                for (int i = 0; i < 2; i++)
                    af[i] = *(const bf16x8*)&Ab[(wm * 32 + i * 16 + cidx) * 64 + pb * 8];
#pragma unroll
                for (int j = 0; j < 2; j++)
                    bfr[j] = *(const bf16x8*)&Bb[(wn * 32 + j * 16 + cidx) * 64 + pb * 8];
                __builtin_amdgcn_s_setprio(1);
#pragma unroll
                for (int i = 0; i < 2; i++)
#pragma unroll
                    for (int j = 0; j < 2; j++)
                        ac[i][j] = __builtin_amdgcn_mfma_f32_16x16x32_bf16(af[i], bfr[j], ac[i][j], 0, 0, 0);
                __builtin_amdgcn_s_setprio(0);
            }
            __syncthreads();             // reads of cur done + prefetch landed
            cur ^= 1;
        }
    };

    run_pass(Bg0, acc);
    if (MODE == 5) {
        const bf16* B2g = (const bf16*)resv + (size_t)(n0 + w * 8 + lrow) * K + lcb * 8;
        run_pass(B2g, acc2);
    }

    int rbase = quad * 4;
#pragma unroll
    for (int i = 0; i < 2; i++) {
#pragma unroll
        for (int j = 0; j < 2; j++) {
#pragma unroll
            for (int r = 0; r < 4; r++) {
                int row = m0 + wm * 32 + i * 16 + rbase + r;
                int col = n0 + wn * 32 + j * 16 + cidx;
                float v = acc[i][j][r];
                size_t idx = (size_t)row * N + col;
                if (MODE == 1) {
                    int h = col >> 6, kk = col & 63;
                    float outv = v;
                    if (rope) {
                        float other = __shfl_xor(v, 1);
                        float p = (float)(kk >> 1);
                        float theta = __expf(p * -0.5756462732485114f); // ln(1e4)/16
                        float ang = (float)row * theta;
                        float c, sn; __sincosf(ang, &sn, &c);
                        outv = (kk & 1) ? (v * c + other * sn) : (v * c - other * sn);
                    }
                    Cq[((size_t)h * 2048 + row) * 64 + kk] = __float2bfloat16(outv);
                } else if (MODE == 2) {
                    v += ((const float*)resv)[idx];
                    ((bf16*)Cv)[idx] = __float2bfloat16(v);
                } else if (MODE == 5) {
                    float g2 = acc2[i][j][r];
                    float sg = 1.f / (1.f + __expf(-v));
                    ((bf16*)Cv)[idx] = __float2bfloat16(v * sg * g2);
                } else {
                    v += __bfloat162float(((const bf16*)resv)[idx]);
                    ((float*)Cv)[idx] = v;
                }
            }
        }
    }
}

// ---------------------------------------------------------------------------
// MFMA causal flash attention (single batch). hd=64.
// q,k: [16][2048][64] bf16 (RoPE'd); vt: [16][64][2048] bf16 (V^T).
// Output o: [2048][1024] bf16 (concat heads).
//  - qt remap pairs heavy+light q-tiles on the same CU.
//  - Swapped QK^T (S^T = K*Q): lane owns one q-row; softmax in-lane + 2 shfl.
//  - log2-domain softmax (Q pre-scaled by 0.125*log2e, exp2 hw op).
//  - P^T via wave-private LDS strip (b64 writes / b128 reads, bank-uniform).
//  - Next K/V tile prefetched into registers after the write barrier.
// ---------------------------------------------------------------------------
__global__ __launch_bounds__(256) void attn_kernel(
    const bf16* __restrict__ q, const bf16* __restrict__ k,
    const bf16* __restrict__ vt, bf16* __restrict__ o)
{
    const int S = 2048;
    __shared__ bf16 Ks[64][72];
    __shared__ bf16 Vs[64][72];                        // V^T tile: [d][s]
    __shared__ __align__(16) char QPbuf[64 * 72 * 2];  // Q stage -> per-wave P strip

    int h = blockIdx.y;
    int qt = (h & 8) ? (int)blockIdx.x : 31 - (int)blockIdx.x;
    int tid = threadIdx.x, lane = tid & 63, w = tid >> 6;
    int quad = lane >> 4, cidx = lane & 15;
    int m0 = qt * 64;

    const bf16* qb = q + ((size_t)h * S + m0) * 64;
    const bf16* kb = k + (size_t)h * S * 64;
    const bf16* vtb = vt + (size_t)h * 64 * S;

    int srow = tid >> 2;
    int sg = (tid & 3) * 16;

    bf16 (*Qs)[72] = (bf16 (*)[72])QPbuf;
    {
        const uint4* src = (const uint4*)(qb + (size_t)srow * 64 + sg);
        uint4 u0 = src[0], u1 = src[1];
        float f[16]; unpack8(u0, f); unpack8(u1, f + 8);
#pragma unroll
        for (int i = 0; i < 16; i++) f[i] *= 0.125f * 1.44269504f;
        *(uint4*)&Qs[srow][sg] = packbf8(f);
        *(uint4*)&Qs[srow][sg + 8] = packbf8(f + 8);
    }
    bf16x8 bQ0 = *(const bf16x8*)&Qs[w * 16 + cidx][quad * 8];
    bf16x8 bQ1 = *(const bf16x8*)&Qs[w * 16 + cidx][32 + quad * 8];

    unsigned* Pst = (unsigned*)QPbuf + w * 576;

    float m_i = -INFINITY, l_i = 0.f;
    f32x4 Oc[4];
#pragma unroll
    for (int i = 0; i < 4; i++) Oc[i] = (f32x4){0.f, 0.f, 0.f, 0.f};

    uint4 ka0, ka1, va0, va1;
    {
        const uint4* ksrc = (const uint4*)(kb + (size_t)srow * 64 + sg);
        ka0 = ksrc[0]; ka1 = ksrc[1];
        const uint4* vsrc = (const uint4*)(vtb + (size_t)srow * S + sg);
        va0 = vsrc[0]; va1 = vsrc[1];
    }

    for (int kt = 0; kt <= qt; kt++) {
        __syncthreads();
        *(uint4*)&Ks[srow][sg] = ka0; *(uint4*)&Ks[srow][sg + 8] = ka1;
        *(uint4*)&Vs[srow][sg] = va0; *(uint4*)&Vs[srow][sg + 8] = va1;
        __syncthreads();
        if (kt < qt) {
            const uint4* kn = (const uint4*)(kb + (size_t)((kt + 1) * 64 + srow) * 64 + sg);
            ka0 = kn[0]; ka1 = kn[1];
            const uint4* vn = (const uint4*)(vtb + (size_t)srow * S + (kt + 1) * 64 + sg);
            va0 = vn[0]; va1 = vn[1];
        }

        f32x4 sc[4];
#pragma unroll
        for (int i = 0; i < 4; i++) {
            bf16x8 aK0 = *(const bf16x8*)&Ks[i * 16 + cidx][quad * 8];
            bf16x8 aK1 = *(const bf16x8*)&Ks[i * 16 + cidx][32 + quad * 8];
            f32x4 z = (f32x4){0.f, 0.f, 0.f, 0.f};
            z = __builtin_amdgcn_mfma_f32_16x16x32_bf16(aK0, bQ0, z, 0, 0, 0);
            z = __builtin_amdgcn_mfma_f32_16x16x32_bf16(aK1, bQ1, z, 0, 0, 0);
            sc[i] = z;
        }

        if (kt == qt) {
#pragma unroll
            for (int i = 0; i < 4; i++)
#pragma unroll
                for (int r = 0; r < 4; r++)
                    if (i * 16 + quad * 4 + r > w * 16 + cidx) sc[i][r] = -INFINITY;
        }

        float pmax = sc[0][0];
#pragma unroll
        for (int i = 0; i < 4; i++)
#pragma unroll
            for (int r = 0; r < 4; r++) pmax = fmaxf(pmax, sc[i][r]);
        pmax = fmaxf(pmax, __shfl_xor(pmax, 16));
        pmax = fmaxf(pmax, __shfl_xor(pmax, 32));
        float mnew = fmaxf(m_i, pmax);
        float alpha = __builtin_amdgcn_exp2f(m_i - mnew);
        float rs = 0.f;
#pragma unroll
        for (int i = 0; i < 4; i++)
#pragma unroll
            for (int r = 0; r < 4; r++) {
                sc[i][r] = __builtin_amdgcn_exp2f(sc[i][r] - mnew);
                rs += sc[i][r];
            }
        rs += __shfl_xor(rs, 16);
        rs += __shfl_xor(rs, 32);
        l_i = l_i * alpha + rs;
        m_i = mnew;
#pragma unroll
        for (int i = 0; i < 4; i++) {
            Oc[i][0] *= alpha; Oc[i][1] *= alpha;
            Oc[i][2] *= alpha; Oc[i][3] *= alpha;
        }

#pragma unroll
        for (int i = 0; i < 4; i++) {
            uint2 t;
            t.x = pack2(sc[i][0], sc[i][1]);
            t.y = pack2(sc[i][2], sc[i][3]);
            *(uint2*)&Pst[cidx * 36 + 8 * i + 2 * quad] = t;
        }
        bf16x8 bP0 = *(const bf16x8*)&Pst[cidx * 36 + 4 * quad];
        bf16x8 bP1 = *(const bf16x8*)&Pst[cidx * 36 + 16 + 4 * quad];

#pragma unroll
        for (int i = 0; i < 4; i++) {
            bf16x8 aV0 = *(const bf16x8*)&Vs[i * 16 + cidx][quad * 8];
            bf16x8 aV1 = *(const bf16x8*)&Vs[i * 16 + cidx][32 + quad * 8];
            Oc[i] = __builtin_amdgcn_mfma_f32_16x16x32_bf16(aV0, bP0, Oc[i], 0, 0, 0);
            Oc[i] = __builtin_amdgcn_mfma_f32_16x16x32_bf16(aV1, bP1, Oc[i], 0, 0, 0);
        }
    }

    float inv = 1.f / l_i;
#pragma unroll
    for (int i = 0; i < 4; i++) {
        uint2 t;
        t.x = pack2(Oc[i][0] * inv, Oc[i][1] * inv);
        t.y = pack2(Oc[i][2] * inv, Oc[i][3] * inv);
        *(uint2*)&Pst[cidx * 36 + 8 * i + 2 * quad] = t;
    }
    int r2 = lane >> 2, g2 = (lane & 3) * 8;
    uint4 o0 = *(const uint4*)&Pst[r2 * 36 + g2];
    uint4 o1 = *(const uint4*)&Pst[r2 * 36 + g2 + 4];
    bf16* orow = o + (size_t)(m0 + w * 16 + r2) * 1024 + h * 64;
    *(uint4*)(orow + g2 * 2) = o0;
    *(uint4*)(orow + g2 * 2 + 8) = o1;
}

// ---------------------------------------------------------------------------
extern "C" void kernel_launch(void* const* d_in, const int* in_sizes, int n_in,
                              void* d_out, int out_size, void* d_ws, size_t ws_size,
                              hipStream_t stream)
{
    const int S = 2048, D = 1024;

    const float* x    = (const float*)d_in[0];
    const float* ln1g = (const float*)d_in[1];
    const float* ln1b = (const float*)d_in[2];
    const float* Wq   = (const float*)d_in[3];
    const float* Wk   = (const float*)d_in[4];
    const float* Wv   = (const float*)d_in[5];
    const float* Wo   = (const float*)d_in[6];
    const float* ln2g = (const float*)d_in[7];
    const float* ln2b = (const float*)d_in[8];
    const float* W1   = (const float*)d_in[9];
    const float* W2   = (const float*)d_in[10];
    const float* W3   = (const float*)d_in[11];
    float* out = (float*)d_out;

    const size_t NR = (size_t)S * D;   // 2M elems per 4MB region
    bf16* r0 = (bf16*)d_ws;
    bf16* r1 = r0 + NR;
    bf16* r2 = r1 + NR;
    bf16* r3 = r2 + NR;
    const size_t M1 = 1u << 20;        // 1M elems

    for (int b = 0; b < 2; b++) {
        const float* xb = x + (size_t)b * S * D;
        float* ob = out + (size_t)b * S * D;   // 8 MB scratch / final out
        bf16* obB = (bf16*)ob;

        // 1. h = LN1(xb) -> r3
        ln_kernel<float, bf16><<<S, 256, 0, stream>>>(xb, ln1g, ln1b, r3);

        // 2. WqT/WkT/WvT -> obB[0:3M)  (single fused dispatch)
        tconv3_kernel<<<dim3(2, 32, 48), 256, 0, stream>>>(Wq, Wk, Wv, obB);

        // 3. q,k,v (+RoPE) -> r0,r1,r2
        mfma_gemm<1><<<dim3(16, 32, 3), 256, 0, stream>>>(r3, obB, r0, nullptr, S, 1024, 1024);

        // 4. V^T -> obB[0:2M)  (WqT/WkT dead)
        vtrans_kernel<<<dim3(32, 16), 256, 0, stream>>>(r2, obB);

        // 5. attn -> r2 (V natural dead)
        attn_kernel<<<dim3(32, 16), 256, 0, stream>>>(r0, r1, obB, r2);

        // 6. WoT -> obB[2M:3M) (WvT dead); x2 = xb + attn@Wo -> r3
        tconv_kernel<<<dim3(32, 32, 1), 256, 0, stream>>>(Wo, obB + 2 * M1, 1024, 1024);
        mfma_gemm<2><<<dim3(16, 32, 1), 256, 0, stream>>>(r2, obB + 2 * M1, r3, xb, S, 1024, 1024);

        // 7. h2 = LN2(r3) -> r0
        ln_kernel<bf16, bf16><<<S, 256, 0, stream>>>(r3, ln2g, ln2b, r0);

        // 8. W1T -> obB[0:2M) (Vt dead), W2T -> obB[2M:4M) (WoT dead)
        tconv_kernel<<<dim3(64, 32, 1), 256, 0, stream>>>(W1, obB,          1024, 2048);
        tconv_kernel<<<dim3(64, 32, 1), 256, 0, stream>>>(W2, obB + 2 * M1, 1024, 2048);

        // 9. sb = silu(h2@W1) * (h2@W2) -> r1 (spans r1..r2)  [fused SwiGLU]
        mfma_gemm<5><<<dim3(32, 32, 1), 256, 0, stream>>>(r0, obB, r1, obB + 2 * M1, S, 2048, 1024);

        // 10. W3T -> r0 (h2 dead)
        tconv_kernel<<<dim3(32, 64, 1), 256, 0, stream>>>(W3, r0, 2048, 1024);

        // 11. out = x2 + sb @ W3 -> ob (fp32)
        mfma_gemm<4><<<dim3(16, 32, 1), 256, 0, stream>>>(r1, r0, ob, r3, S, 1024, 2048);
    }
}

// Round 4
// 368.930 us; speedup vs baseline: 1.7187x; 1.0359x over previous
//
#include <hip/hip_runtime.h>
#include <hip/hip_bf16.h>

using bf16 = __hip_bfloat16;
typedef __attribute__((ext_vector_type(8))) short bf16x8;
typedef __attribute__((ext_vector_type(4))) float f32x4;

// Shapes fixed: B=2, S=2048, D=1024, H=16, hd=64, F=2048.
// Global I/O fp32. Batches sequential. ws = 16 MB = 4 bf16 regions r0..r3
// (2M elems each). Per-batch out half pb (8 MB = 4M bf16) doubles as scratch.
//
// Per-batch lifetimes (stream-ordered, audited):
//  1  LN1(xb)            -> r3
//  2  tconv_w: WqT/WkT/WvT/WoT -> pb[0:1M)/[1M:2M)/[2M:3M)/[3M:4M)
//  3  QKV mfma (z=0,1,2) -> q=r0, k=r1, vt=r2 (z=2 writes V^T directly;
//                           rope z<2)
//  4  attn(r0,r1,vt=r2)  -> ao = pb[0:2M)   (WqT/WkT dead)
//  5  mode2: A=ao, B=WoT(pb+3M), res=xb -> x2 = r3  (h dead)
//  6  LN2(r3)            -> h2 = r0 (q dead)
//  7  tconv12: W1T -> pb[0:2M) (ao dead), W2T -> pb[2M:4M) (WvT/WoT dead)
//  8  mode5 dual-B: A=r0, B1=W1T, B2=W2T -> sb = silu(u)*g -> r1 (r1..r2)
//  9  tconv: W3T -> r0 (h2 dead)
// 10  mode4: A=r1(sb), B=r0(W3T), res=r3(x2) -> ob fp32 (final, overwrites pb)

__device__ inline float toF(float x) { return x; }
__device__ inline float toF(bf16 x) { return __bfloat162float(x); }
__device__ inline void  stV(float* p, float v) { *p = v; }
__device__ inline void  stV(bf16* p, float v) { *p = __float2bfloat16(v); }

__device__ __forceinline__ void unpack8(uint4 u, float* f) {
    f[0] = __uint_as_float(u.x << 16); f[1] = __uint_as_float(u.x & 0xffff0000u);
    f[2] = __uint_as_float(u.y << 16); f[3] = __uint_as_float(u.y & 0xffff0000u);
    f[4] = __uint_as_float(u.z << 16); f[5] = __uint_as_float(u.z & 0xffff0000u);
    f[6] = __uint_as_float(u.w << 16); f[7] = __uint_as_float(u.w & 0xffff0000u);
}

__device__ __forceinline__ uint4 packbf8(const float* f) {
    union { unsigned short u[8]; uint4 v; } r;
#pragma unroll
    for (int i = 0; i < 8; i++) {
        bf16 b = __float2bfloat16(f[i]);
        r.u[i] = *(unsigned short*)&b;
    }
    return r.v;
}

__device__ __forceinline__ unsigned pack2(float lo, float hi) {
    bf16 a = __float2bfloat16(lo), b = __float2bfloat16(hi);
    return ((unsigned)*(unsigned short*)&b << 16) | (unsigned)*(unsigned short*)&a;
}

__device__ __forceinline__ void gl_lds16(const void* g, void* l) {
    __builtin_amdgcn_global_load_lds(
        (__attribute__((address_space(1))) void*)g,
        (__attribute__((address_space(3))) void*)l, 16, 0, 0);
}

// ---------------------------------------------------------------------------
// LayerNorm: one block per row, D=1024, 256 threads.
// ---------------------------------------------------------------------------
template <typename Tx, typename To>
__global__ __launch_bounds__(256) void ln_kernel(
    const Tx* __restrict__ x, const float* __restrict__ g,
    const float* __restrict__ b, To* __restrict__ out)
{
    const int D = 1024;
    int row = blockIdx.x;
    int tid = threadIdx.x;
    const Tx* xr = x + (size_t)row * D;

    float vals[4];
    float sum = 0.f, sumsq = 0.f;
#pragma unroll
    for (int i = 0; i < 4; i++) {
        float v = toF(xr[tid + i * 256]);
        vals[i] = v; sum += v; sumsq += v * v;
    }
#pragma unroll
    for (int off = 32; off > 0; off >>= 1) {
        sum += __shfl_xor(sum, off);
        sumsq += __shfl_xor(sumsq, off);
    }
    __shared__ float s1[4], s2[4];
    int wave = tid >> 6, lane = tid & 63;
    if (lane == 0) { s1[wave] = sum; s2[wave] = sumsq; }
    __syncthreads();
    sum = s1[0] + s1[1] + s1[2] + s1[3];
    sumsq = s2[0] + s2[1] + s2[2] + s2[3];

    float mu = sum * (1.f / D);
    float var = sumsq * (1.f / D) - mu * mu;
    float rstd = rsqrtf(var + 1e-5f);

    To* orow = out + (size_t)row * D;
#pragma unroll
    for (int i = 0; i < 4; i++) {
        int c = tid + i * 256;
        stV(&orow[c], (vals[i] - mu) * rstd * g[c] + b[c]);
    }
}

// ---------------------------------------------------------------------------
// Generic transpose+convert: in fp32 [R][C] (per z-slice) -> out bf16 [C][R].
// (used for W3)
// ---------------------------------------------------------------------------
__global__ __launch_bounds__(256) void tconv_kernel(
    const float* __restrict__ in, bf16* __restrict__ out, int R, int C)
{
    __shared__ float t[32][33];
    int hh = blockIdx.z;
    const float* ip = in + (size_t)hh * R * C;
    bf16* op = out + (size_t)hh * R * C;
    int c0 = blockIdx.x * 32, r0 = blockIdx.y * 32;
    int tx = threadIdx.x & 31, ty = threadIdx.x >> 5;  // ty 0..7
#pragma unroll
    for (int i = 0; i < 4; i++)
        t[ty + 8 * i][tx] = ip[(size_t)(r0 + ty + 8 * i) * C + c0 + tx];
    __syncthreads();
#pragma unroll
    for (int i = 0; i < 4; i++)
        op[(size_t)(c0 + ty + 8 * i) * R + r0 + tx] = __float2bfloat16(t[tx][ty + 8 * i]);
}

// ---------------------------------------------------------------------------
// Fused Wq/Wk/Wv/Wo transpose. z in [0,64): 64 output slices of [64][1024]
// at out + z*64K elems.
//  z<48:  Wq/Wk/Wv head (z&15): in [1024][64] contiguous, ldi=64
//  z>=48: Wo col-slice (z-48):  in = Wo + (z-48)*64, ldi=1024
// ---------------------------------------------------------------------------
__global__ __launch_bounds__(256) void tconv_w_kernel(
    const float* __restrict__ Aq, const float* __restrict__ Ak,
    const float* __restrict__ Av, const float* __restrict__ Ao,
    bf16* __restrict__ out)
{
    __shared__ float t[32][33];
    int z = blockIdx.z;
    const float* ip; int ldi;
    if (z < 48) {
        const float* s = (z < 16) ? Aq : (z < 32) ? Ak : Av;
        ip = s + (size_t)(z & 15) * 65536; ldi = 64;
    } else {
        ip = Ao + (size_t)(z - 48) * 64; ldi = 1024;
    }
    bf16* op = out + ((size_t)z << 16);
    int c0 = blockIdx.x * 32, r0 = blockIdx.y * 32;
    int tx = threadIdx.x & 31, ty = threadIdx.x >> 5;
#pragma unroll
    for (int i = 0; i < 4; i++)
        t[ty + 8 * i][tx] = ip[(size_t)(r0 + ty + 8 * i) * ldi + c0 + tx];
    __syncthreads();
#pragma unroll
    for (int i = 0; i < 4; i++)
        op[(size_t)(c0 + ty + 8 * i) * 1024 + r0 + tx] = __float2bfloat16(t[tx][ty + 8 * i]);
}

// Fused W1/W2 transpose: z in {0,1}; in [1024][2048] -> out bf16 [2048][1024]
// at out + z*2M elems.
__global__ __launch_bounds__(256) void tconv12_kernel(
    const float* __restrict__ W1, const float* __restrict__ W2,
    bf16* __restrict__ out)
{
    __shared__ float t[32][33];
    int z = blockIdx.z;
    const float* ip = z ? W2 : W1;
    bf16* op = out + ((size_t)z << 21);
    int c0 = blockIdx.x * 32, r0 = blockIdx.y * 32;
    int tx = threadIdx.x & 31, ty = threadIdx.x >> 5;
#pragma unroll
    for (int i = 0; i < 4; i++)
        t[ty + 8 * i][tx] = ip[(size_t)(r0 + ty + 8 * i) * 2048 + c0 + tx];
    __syncthreads();
#pragma unroll
    for (int i = 0; i < 4; i++)
        op[(size_t)(c0 + ty + 8 * i) * 1024 + r0 + tx] = __float2bfloat16(t[tx][ty + 8 * i]);
}

// ---------------------------------------------------------------------------
// MFMA GEMM: C[M,N] = A[M,K](bf16) @ B (BT[N,K] bf16), fp32 accum.
// 64x64 tile, BK=64 double-buffer, 4 waves (2x2), wave tile 32x32.
// Source-pre-swizzled LDS (conflict-free ds_read_b128), setprio around MFMA.
//
// MODE 1: QKV. z=0,1: scatter [H][S][64] + RoPE. z=2: direct V^T write
//         [H][64][S] (packed 4-row uint2 stores), no rope.
// MODE 2: C bf16 = acc + resF32
// MODE 4: C f32  = acc + resBf16
// MODE 5: fused SwiGLU, dual-B single pass (B1=BT0, B2=resv):
//         C bf16 = silu(acc) * acc2.  LDS 3 matrices/buf (48KB).
// ---------------------------------------------------------------------------
template <int MODE>
__global__ __launch_bounds__(256) void mfma_gemm(
    const bf16* __restrict__ A, const bf16* __restrict__ BT0,
    void* __restrict__ Cv, const void* __restrict__ resv,
    int M, int N, int K)
{
    constexpr int NB = (MODE == 5) ? 3 : 2;            // matrices per buffer
    __shared__ bf16 smem[2][NB][64 * 64];              // 32KB / 48KB
    int tid = threadIdx.x, lane = tid & 63, w = tid >> 6;
    int wm = w >> 1, wn = w & 1;
    int m0 = blockIdx.y * 64, n0 = blockIdx.x * 64;

    const bf16* BT = BT0;
    bf16* Cq = nullptr; int rope = 0;
    if (MODE == 1) {
        int z = blockIdx.z;
        BT = BT0 + ((size_t)z << 20);
        Cq = (bf16*)Cv + ((size_t)z << 21);
        rope = (z < 2);
    }

    // staging: wave w covers rows w*8+lrow and +32; 16B col-block
    // pre-swizzled on the GLOBAL source so linear LDS write == swizzled layout
    int lrow = lane >> 3;                  // 0..7
    int lcb  = (lane & 7) ^ lrow;          // pre-swizzled 16B col-block
    const bf16* Ag  = A  + (size_t)(m0 + w * 8 + lrow) * K + lcb * 8;
    const bf16* Bg0 = BT + (size_t)(n0 + w * 8 + lrow) * K + lcb * 8;
    const bf16* B2g = (MODE == 5)
        ? (const bf16*)resv + (size_t)(n0 + w * 8 + lrow) * K + lcb * 8
        : nullptr;
    unsigned sbase = (unsigned)__builtin_amdgcn_readfirstlane(w * 8 * 128);
    char* smc = (char*)smem;

    f32x4 acc[2][2], acc2[2][2];
#pragma unroll
    for (int i = 0; i < 2; i++)
#pragma unroll
        for (int j = 0; j < 2; j++) {
            acc[i][j] = (f32x4){0.f, 0.f, 0.f, 0.f};
            if (MODE == 5) acc2[i][j] = (f32x4){0.f, 0.f, 0.f, 0.f};
        }

    int cidx = lane & 15, quad = lane >> 4;

    auto STAGE = [&](int buf, int k0) {
        char* p = smc + (size_t)buf * (NB * 8192) + sbase;
        gl_lds16(Ag + k0,                   p);
        gl_lds16(Ag + (size_t)32 * K + k0,  p + 4096);
        gl_lds16(Bg0 + k0,                  p + 8192);
        gl_lds16(Bg0 + (size_t)32 * K + k0, p + 12288);
        if (MODE == 5) {
            gl_lds16(B2g + k0,                  p + 16384);
            gl_lds16(B2g + (size_t)32 * K + k0, p + 20480);
        }
    };

    STAGE(0, 0);
    __syncthreads();                 // drains vmcnt, publishes buf0
    int cur = 0;
    for (int k0 = 0; k0 < K; k0 += 64) {
        if (k0 + 64 < K) STAGE(cur ^ 1, k0 + 64);   // prefetch next
        const bf16* Ab = (const bf16*)(smc + (size_t)cur * (NB * 8192));
        const bf16* Bb = Ab + 4096;
        const bf16* B2b = Ab + 8192;
#pragma unroll
        for (int kk = 0; kk < 2; kk++) {
            int pb = (kk * 4 + quad) ^ (cidx & 7);  // swizzled slot
            bf16x8 af[2], bfr[2], b2f[2];
#pragma unroll
            for (int i = 0; i < 2; i++)
                af[i] = *(const bf16x8*)&Ab[(wm * 32 + i * 16 + cidx) * 64 + pb * 8];
#pragma unroll
            for (int j = 0; j < 2; j++)
                bfr[j] = *(const bf16x8*)&Bb[(wn * 32 + j * 16 + cidx) * 64 + pb * 8];
            if (MODE == 5) {
#pragma unroll
                for (int j = 0; j < 2; j++)
                    b2f[j] = *(const bf16x8*)&B2b[(wn * 32 + j * 16 + cidx) * 64 + pb * 8];
            }
            __builtin_amdgcn_s_setprio(1);
#pragma unroll
            for (int i = 0; i < 2; i++)
#pragma unroll
                for (int j = 0; j < 2; j++) {
                    acc[i][j] = __builtin_amdgcn_mfma_f32_16x16x32_bf16(af[i], bfr[j], acc[i][j], 0, 0, 0);
                    if (MODE == 5)
                        acc2[i][j] = __builtin_amdgcn_mfma_f32_16x16x32_bf16(af[i], b2f[j], acc2[i][j], 0, 0, 0);
                }
            __builtin_amdgcn_s_setprio(0);
        }
        __syncthreads();             // reads of cur done + prefetch landed
        cur ^= 1;
    }

    int rbase = quad * 4;
#pragma unroll
    for (int i = 0; i < 2; i++) {
#pragma unroll
        for (int j = 0; j < 2; j++) {
            int row0 = m0 + wm * 32 + i * 16 + rbase;
            int col = n0 + wn * 32 + j * 16 + cidx;
            if (MODE == 1 && !rope) {
                // z==2: direct V^T write vt[h][d][s], 4 consecutive s packed
                int h_ = col >> 6, d = col & 63;
                uint2 t;
                t.x = pack2(acc[i][j][0], acc[i][j][1]);
                t.y = pack2(acc[i][j][2], acc[i][j][3]);
                *(uint2*)&Cq[(size_t)h_ * 131072 + (size_t)d * 2048 + row0] = t;
                continue;
            }
#pragma unroll
            for (int r = 0; r < 4; r++) {
                int row = row0 + r;
                float v = acc[i][j][r];
                size_t idx = (size_t)row * N + col;
                if (MODE == 1) {
                    int h_ = col >> 6, kk = col & 63;
                    float other = __shfl_xor(v, 1);
                    float p = (float)(kk >> 1);
                    float theta = __expf(p * -0.5756462732485114f); // ln(1e4)/16
                    float ang = (float)row * theta;
                    float c, sn; __sincosf(ang, &sn, &c);
                    float outv = (kk & 1) ? (v * c + other * sn) : (v * c - other * sn);
                    Cq[((size_t)h_ * 2048 + row) * 64 + kk] = __float2bfloat16(outv);
                } else if (MODE == 2) {
                    v += ((const float*)resv)[idx];
                    ((bf16*)Cv)[idx] = __float2bfloat16(v);
                } else if (MODE == 5) {
                    float g2 = acc2[i][j][r];
                    float sg = 1.f / (1.f + __expf(-v));
                    ((bf16*)Cv)[idx] = __float2bfloat16(v * sg * g2);
                } else {
                    v += __bfloat162float(((const bf16*)resv)[idx]);
                    ((float*)Cv)[idx] = v;
                }
            }
        }
    }
}

// ---------------------------------------------------------------------------
// MFMA causal flash attention (single batch). hd=64.
// q,k: [16][2048][64] bf16 (RoPE'd); vt: [16][64][2048] bf16 (V^T).
// Output o: [2048][1024] bf16 (concat heads).
//  - qt remap pairs heavy+light q-tiles on the same CU.
//  - Swapped QK^T (S^T = K*Q): lane owns one q-row; softmax in-lane + 2 shfl.
//  - log2-domain softmax (Q pre-scaled by 0.125*log2e, exp2 hw op).
//  - P^T via wave-private LDS strip (b64 writes / b128 reads, bank-uniform).
//  - Next K/V tile prefetched into registers after the write barrier.
// ---------------------------------------------------------------------------
__global__ __launch_bounds__(256) void attn_kernel(
    const bf16* __restrict__ q, const bf16* __restrict__ k,
    const bf16* __restrict__ vt, bf16* __restrict__ o)
{
    const int S = 2048;
    __shared__ bf16 Ks[64][72];
    __shared__ bf16 Vs[64][72];                        // V^T tile: [d][s]
    __shared__ __align__(16) char QPbuf[64 * 72 * 2];  // Q stage -> per-wave P strip

    int h = blockIdx.y;
    int qt = (h & 8) ? (int)blockIdx.x : 31 - (int)blockIdx.x;
    int tid = threadIdx.x, lane = tid & 63, w = tid >> 6;
    int quad = lane >> 4, cidx = lane & 15;
    int m0 = qt * 64;

    const bf16* qb = q + ((size_t)h * S + m0) * 64;
    const bf16* kb = k + (size_t)h * S * 64;
    const bf16* vtb = vt + (size_t)h * 64 * S;

    int srow = tid >> 2;
    int sg = (tid & 3) * 16;

    bf16 (*Qs)[72] = (bf16 (*)[72])QPbuf;
    {
        const uint4* src = (const uint4*)(qb + (size_t)srow * 64 + sg);
        uint4 u0 = src[0], u1 = src[1];
        float f[16]; unpack8(u0, f); unpack8(u1, f + 8);
#pragma unroll
        for (int i = 0; i < 16; i++) f[i] *= 0.125f * 1.44269504f;
        *(uint4*)&Qs[srow][sg] = packbf8(f);
        *(uint4*)&Qs[srow][sg + 8] = packbf8(f + 8);
    }
    bf16x8 bQ0 = *(const bf16x8*)&Qs[w * 16 + cidx][quad * 8];
    bf16x8 bQ1 = *(const bf16x8*)&Qs[w * 16 + cidx][32 + quad * 8];

    unsigned* Pst = (unsigned*)QPbuf + w * 576;

    float m_i = -INFINITY, l_i = 0.f;
    f32x4 Oc[4];
#pragma unroll
    for (int i = 0; i < 4; i++) Oc[i] = (f32x4){0.f, 0.f, 0.f, 0.f};

    uint4 ka0, ka1, va0, va1;
    {
        const uint4* ksrc = (const uint4*)(kb + (size_t)srow * 64 + sg);
        ka0 = ksrc[0]; ka1 = ksrc[1];
        const uint4* vsrc = (const uint4*)(vtb + (size_t)srow * S + sg);
        va0 = vsrc[0]; va1 = vsrc[1];
    }

    for (int kt = 0; kt <= qt; kt++) {
        __syncthreads();
        *(uint4*)&Ks[srow][sg] = ka0; *(uint4*)&Ks[srow][sg + 8] = ka1;
        *(uint4*)&Vs[srow][sg] = va0; *(uint4*)&Vs[srow][sg + 8] = va1;
        __syncthreads();
        if (kt < qt) {
            const uint4* kn = (const uint4*)(kb + (size_t)((kt + 1) * 64 + srow) * 64 + sg);
            ka0 = kn[0]; ka1 = kn[1];
            const uint4* vn = (const uint4*)(vtb + (size_t)srow * S + (kt + 1) * 64 + sg);
            va0 = vn[0]; va1 = vn[1];
        }

        f32x4 sc[4];
#pragma unroll
        for (int i = 0; i < 4; i++) {
            bf16x8 aK0 = *(const bf16x8*)&Ks[i * 16 + cidx][quad * 8];
            bf16x8 aK1 = *(const bf16x8*)&Ks[i * 16 + cidx][32 + quad * 8];
            f32x4 z = (f32x4){0.f, 0.f, 0.f, 0.f};
            z = __builtin_amdgcn_mfma_f32_16x16x32_bf16(aK0, bQ0, z, 0, 0, 0);
            z = __builtin_amdgcn_mfma_f32_16x16x32_bf16(aK1, bQ1, z, 0, 0, 0);
            sc[i] = z;
        }

        if (kt == qt) {
#pragma unroll
            for (int i = 0; i < 4; i++)
#pragma unroll
                for (int r = 0; r < 4; r++)
                    if (i * 16 + quad * 4 + r > w * 16 + cidx) sc[i][r] = -INFINITY;
        }

        float pmax = sc[0][0];
#pragma unroll
        for (int i = 0; i < 4; i++)
#pragma unroll
            for (int r = 0; r < 4; r++) pmax = fmaxf(pmax, sc[i][r]);
        pmax = fmaxf(pmax, __shfl_xor(pmax, 16));
        pmax = fmaxf(pmax, __shfl_xor(pmax, 32));
        float mnew = fmaxf(m_i, pmax);
        float alpha = __builtin_amdgcn_exp2f(m_i - mnew);
        float rs = 0.f;
#pragma unroll
        for (int i = 0; i < 4; i++)
#pragma unroll
            for (int r = 0; r < 4; r++) {
                sc[i][r] = __builtin_amdgcn_exp2f(sc[i][r] - mnew);
                rs += sc[i][r];
            }
        rs += __shfl_xor(rs, 16);
        rs += __shfl_xor(rs, 32);
        l_i = l_i * alpha + rs;
        m_i = mnew;
#pragma unroll
        for (int i = 0; i < 4; i++) {
            Oc[i][0] *= alpha; Oc[i][1] *= alpha;
            Oc[i][2] *= alpha; Oc[i][3] *= alpha;
        }

#pragma unroll
        for (int i = 0; i < 4; i++) {
            uint2 t;
            t.x = pack2(sc[i][0], sc[i][1]);
            t.y = pack2(sc[i][2], sc[i][3]);
            *(uint2*)&Pst[cidx * 36 + 8 * i + 2 * quad] = t;
        }
        bf16x8 bP0 = *(const bf16x8*)&Pst[cidx * 36 + 4 * quad];
        bf16x8 bP1 = *(const bf16x8*)&Pst[cidx * 36 + 16 + 4 * quad];

#pragma unroll
        for (int i = 0; i < 4; i++) {
            bf16x8 aV0 = *(const bf16x8*)&Vs[i * 16 + cidx][quad * 8];
            bf16x8 aV1 = *(const bf16x8*)&Vs[i * 16 + cidx][32 + quad * 8];
            Oc[i] = __builtin_amdgcn_mfma_f32_16x16x32_bf16(aV0, bP0, Oc[i], 0, 0, 0);
            Oc[i] = __builtin_amdgcn_mfma_f32_16x16x32_bf16(aV1, bP1, Oc[i], 0, 0, 0);
        }
    }

    float inv = 1.f / l_i;
#pragma unroll
    for (int i = 0; i < 4; i++) {
        uint2 t;
        t.x = pack2(Oc[i][0] * inv, Oc[i][1] * inv);
        t.y = pack2(Oc[i][2] * inv, Oc[i][3] * inv);
        *(uint2*)&Pst[cidx * 36 + 8 * i + 2 * quad] = t;
    }
    int r2 = lane >> 2, g2 = (lane & 3) * 8;
    uint4 o0 = *(const uint4*)&Pst[r2 * 36 + g2];
    uint4 o1 = *(const uint4*)&Pst[r2 * 36 + g2 + 4];
    bf16* orow = o + (size_t)(m0 + w * 16 + r2) * 1024 + h * 64;
    *(uint4*)(orow + g2 * 2) = o0;
    *(uint4*)(orow + g2 * 2 + 8) = o1;
}

// ---------------------------------------------------------------------------
extern "C" void kernel_launch(void* const* d_in, const int* in_sizes, int n_in,
                              void* d_out, int out_size, void* d_ws, size_t ws_size,
                              hipStream_t stream)
{
    const int S = 2048, D = 1024;

    const float* x    = (const float*)d_in[0];
    const float* ln1g = (const float*)d_in[1];
    const float* ln1b = (const float*)d_in[2];
    const float* Wq   = (const float*)d_in[3];
    const float* Wk   = (const float*)d_in[4];
    const float* Wv   = (const float*)d_in[5];
    const float* Wo   = (const float*)d_in[6];
    const float* ln2g = (const float*)d_in[7];
    const float* ln2b = (const float*)d_in[8];
    const float* W1   = (const float*)d_in[9];
    const float* W2   = (const float*)d_in[10];
    const float* W3   = (const float*)d_in[11];
    float* out = (float*)d_out;

    const size_t NR = (size_t)S * D;   // 2M elems per 4MB region
    bf16* r0 = (bf16*)d_ws;
    bf16* r1 = r0 + NR;
    bf16* r2 = r1 + NR;
    bf16* r3 = r2 + NR;
    const size_t M1 = 1u << 20;        // 1M elems

    for (int b = 0; b < 2; b++) {
        const float* xb = x + (size_t)b * S * D;
        float* ob = out + (size_t)b * S * D;   // 8 MB scratch / final out
        bf16* pb = (bf16*)ob;

        // 1. h = LN1(xb) -> r3
        ln_kernel<float, bf16><<<S, 256, 0, stream>>>(xb, ln1g, ln1b, r3);

        // 2. WqT/WkT/WvT/WoT -> pb[0:4M)  (single fused dispatch)
        tconv_w_kernel<<<dim3(2, 32, 64), 256, 0, stream>>>(Wq, Wk, Wv, Wo, pb);

        // 3. q,k (+RoPE) -> r0,r1; V^T directly -> r2
        mfma_gemm<1><<<dim3(16, 32, 3), 256, 0, stream>>>(r3, pb, r0, nullptr, S, 1024, 1024);

        // 4. attn -> ao = pb[0:2M)  (WqT/WkT dead; WoT at pb[3M:4M) alive)
        attn_kernel<<<dim3(32, 16), 256, 0, stream>>>(r0, r1, r2, pb);

        // 5. x2 = xb + ao @ Wo -> r3 (h dead)
        mfma_gemm<2><<<dim3(16, 32, 1), 256, 0, stream>>>(pb, pb + 3 * M1, r3, xb, S, 1024, 1024);

        // 6. h2 = LN2(r3) -> r0 (q dead)
        ln_kernel<bf16, bf16><<<S, 256, 0, stream>>>(r3, ln2g, ln2b, r0);

        // 7. W1T -> pb[0:2M) (ao dead), W2T -> pb[2M:4M) (WvT/WoT dead)
        tconv12_kernel<<<dim3(64, 32, 2), 256, 0, stream>>>(W1, W2, pb);

        // 8. sb = silu(h2@W1) * (h2@W2) -> r1 (spans r1..r2; k,vt dead)
        mfma_gemm<5><<<dim3(32, 32, 1), 256, 0, stream>>>(r0, pb, r1, pb + 2 * M1, S, 2048, 1024);

        // 9. W3T -> r0 (h2 dead)
        tconv_kernel<<<dim3(32, 64, 1), 256, 0, stream>>>(W3, r0, 2048, 1024);

        // 10. out = x2 + sb @ W3 -> ob fp32 (final; overwrites pb scratch)
        mfma_gemm<4><<<dim3(16, 32, 1), 256, 0, stream>>>(r1, r0, ob, r3, S, 1024, 2048);
    }
}